// Round 5
// baseline (226.791 us; speedup 1.0000x reference)
//
#include <hip/hip_runtime.h>
#include <hip/hip_bf16.h>
#include <math.h>

// Problem constants
#define BQ   4096
#define D    256
#define NH   8
#define HD   32
#define LN_  64     // neighbors per node
#define DFF  1024
#define EPSV 1e-5f
#define QSCALE 0.17677669529663687f  // HD^-0.5

typedef __attribute__((ext_vector_type(8))) short short8;
typedef __attribute__((ext_vector_type(4))) float f32x4;

// LDS XOR swizzle (G4): spread 512B/128B-stride rows across banks; bijective involution.
#define ESWZ(row, byte) ((byte) ^ (((row) & 7) << 4))

// ---------------- helpers ----------------
__device__ __forceinline__ float wave_sum(float v){
#pragma unroll
  for (int off = 32; off; off >>= 1) v += __shfl_xor(v, off, 64);
  return v;
}
__device__ __forceinline__ unsigned short f2bf(float f){
  unsigned int u = __float_as_uint(f);
  unsigned int r = (u + 0x7FFFu + ((u >> 16) & 1u)) >> 16;   // RNE
  return (unsigned short)r;
}

// ---------------- mega-prep kernel (block-range dispatch) ----------------
// blocks 0-63    : W1 [256][1024] -> W1t bf16 [1024][256]
// blocks 64-127  : W2 [1024][256] -> W2t bf16 [256][1024]
// blocks 128-255 : Mt bf16 [2048][256], Mt[(h,d)][c] = QSCALE*sum_t Wq[c,ht]*Wk[d,ht]; + pb
// blocks 256-383 : Gt bf16 [256][2048], Gt[n][(h,d)] = sum_t Wv[d,ht]*Wo[ht,n]
// block  384     : bo2[n] = bo[n] + sum_j bv[j]*Wo[j,n]
// blocks 385-640 : mask dtype detect -> flagsArr[bid-385] (plain store, poison-proof)
// blocks 641-1664: gather X (f32) + Xb (bf16)
__global__ __launch_bounds__(256) void k_prep(
    const float* __restrict__ Wq, const float* __restrict__ Wk,
    const float* __restrict__ Wv, const float* __restrict__ Wo,
    const float* __restrict__ W1, const float* __restrict__ W2,
    const float* __restrict__ bq, const float* __restrict__ bv,
    const float* __restrict__ bo,
    const int* __restrict__ batch, const float* __restrict__ emb,
    const unsigned int* __restrict__ maskw,
    unsigned short* __restrict__ W1t, unsigned short* __restrict__ W2t,
    unsigned short* __restrict__ Mt, unsigned short* __restrict__ Gt,
    float* __restrict__ pb, float* __restrict__ bo2,
    float* __restrict__ X, unsigned short* __restrict__ Xb,
    int* __restrict__ flagsArr){
  __shared__ float smem[4224];
  const int bid = blockIdx.x;
  const int tid = threadIdx.x;

  if (bid < 128){
    const float* src; unsigned short* dst; int K, N, t0;
    if (bid < 64){ src = W1; dst = W1t; K = 256;  N = 1024; t0 = bid; }
    else         { src = W2; dst = W2t; K = 1024; N = 256;  t0 = bid - 64; }
    const int ntx = N / 64;
    const int k0 = (t0 / ntx) * 64, n0 = (t0 % ntx) * 64;
    float (*Ts)[65] = (float(*)[65])smem;
    {
      int r = tid >> 2, c4 = (tid & 3) * 16;
#pragma unroll
      for (int i = 0; i < 4; i++)
        *(float4*)&Ts[r][c4 + i * 4] = *(const float4*)(src + (size_t)(k0 + r) * N + n0 + c4 + i * 4);
    }
    __syncthreads();
    {
      int n = tid >> 2, kc = (tid & 3) * 16;
      unsigned int pk[8];
#pragma unroll
      for (int i = 0; i < 8; i++){
        unsigned int lo = f2bf(Ts[kc + 2 * i][n]);
        unsigned int hi = f2bf(Ts[kc + 2 * i + 1][n]);
        pk[i] = lo | (hi << 16);
      }
      unsigned short* orow = dst + (size_t)(n0 + n) * K + k0 + kc;
      *(uint4*)(orow)     = *(uint4*)&pk[0];
      *(uint4*)(orow + 8) = *(uint4*)&pk[4];
    }
    return;
  }
  if (bid < 256){
    int t0 = bid - 128;
    int hd0 = (t0 & 31) * 64, c0 = (t0 >> 5) * 64;
    int h = hd0 >> 8, d0 = hd0 & 255;
    float (*WqS)[33] = (float(*)[33])smem;
    float (*WkS)[33] = (float(*)[33])(smem + 64 * 33);
#pragma unroll
    for (int s = 0; s < 2; s++){
      int idx = tid + s * 256;
      int row = idx >> 3, c4 = (idx & 7) * 4;
      *(float4*)&WqS[row][c4] = *(const float4*)(Wq + (size_t)(c0 + row) * 256 + h * 32 + c4);
      *(float4*)&WkS[row][c4] = *(const float4*)(Wk + (size_t)(d0 + row) * 256 + h * 32 + c4);
    }
    __syncthreads();
    int jo = (tid >> 4) * 4, io = (tid & 15) * 4;
    float acc[4][4];
#pragma unroll
    for (int j = 0; j < 4; j++)
#pragma unroll
      for (int i = 0; i < 4; i++) acc[j][i] = 0.f;
#pragma unroll
    for (int t = 0; t < 32; t++){
#pragma unroll
      for (int j = 0; j < 4; j++){
        float kv = WkS[jo + j][t];
#pragma unroll
        for (int i = 0; i < 4; i++) acc[j][i] = fmaf(kv, WqS[io + i][t], acc[j][i]);
      }
    }
#pragma unroll
    for (int j = 0; j < 4; j++){
      uint2 o;
      o.x = (unsigned)f2bf(acc[j][0] * QSCALE) | ((unsigned)f2bf(acc[j][1] * QSCALE) << 16);
      o.y = (unsigned)f2bf(acc[j][2] * QSCALE) | ((unsigned)f2bf(acc[j][3] * QSCALE) << 16);
      *(uint2*)(Mt + (size_t)(hd0 + jo + j) * 256 + c0 + io) = o;
    }
    if (c0 == 0 && tid < 64){
      float s = 0.f;
#pragma unroll
      for (int t = 0; t < 32; t++) s = fmaf(WkS[tid][t], bq[h * 32 + t], s);
      pb[hd0 + tid] = s * QSCALE;
    }
    return;
  }
  if (bid < 384){
    int t0 = bid - 256;
    int hd0 = (t0 & 31) * 64, n0 = (t0 >> 5) * 64;
    int h = hd0 >> 8, d0 = hd0 & 255;
    float (*WvS)[33] = (float(*)[33])smem;
    float (*WoS)[65] = (float(*)[65])(smem + 64 * 33);
#pragma unroll
    for (int s = 0; s < 2; s++){
      int idx = tid + s * 256;
      int row = idx >> 3, c4 = (idx & 7) * 4;
      *(float4*)&WvS[row][c4] = *(const float4*)(Wv + (size_t)(d0 + row) * 256 + h * 32 + c4);
      int row2 = idx >> 4, c42 = (idx & 15) * 4;
      *(float4*)&WoS[row2][c42] = *(const float4*)(Wo + (size_t)(h * 32 + row2) * 256 + n0 + c42);
    }
    __syncthreads();
    int jo = (tid >> 4) * 4, io = (tid & 15) * 4;
    float acc[4][4];
#pragma unroll
    for (int i = 0; i < 4; i++)
#pragma unroll
      for (int j = 0; j < 4; j++) acc[i][j] = 0.f;
#pragma unroll
    for (int t = 0; t < 32; t++){
#pragma unroll
      for (int i = 0; i < 4; i++){
        float ov = WoS[t][io + i];
#pragma unroll
        for (int j = 0; j < 4; j++) acc[i][j] = fmaf(ov, WvS[jo + j][t], acc[i][j]);
      }
    }
#pragma unroll
    for (int i = 0; i < 4; i++){
      uint2 o;
      o.x = (unsigned)f2bf(acc[i][0]) | ((unsigned)f2bf(acc[i][1]) << 16);
      o.y = (unsigned)f2bf(acc[i][2]) | ((unsigned)f2bf(acc[i][3]) << 16);
      *(uint2*)(Gt + (size_t)(n0 + io + i) * 2048 + hd0 + jo) = o;
    }
    return;
  }
  if (bid == 384){
    int n = tid;
    float s = bo[n];
    for (int j = 0; j < 256; j++) s = fmaf(bv[j], Wo[(size_t)j * 256 + n], s);
    bo2[n] = s;
    return;
  }
  if (bid < 641){
    // ---- mask dtype detect; per-block plain store (no pre-zero needed) ----
    int* df = (int*)smem;
    if (tid == 0) df[0] = 0;
    __syncthreads();
    int idx = (bid - 385) * 256 + tid;
    unsigned int v = maskw[idx];
    int bits = 0;
    if (v == 0x3F800000u) bits = 2;
    else if (v & 0xFFFFFF00u) bits = 1;
    int b2 = __any(bits & 2) ? 2 : 0;
    int b1 = __any(bits & 1) ? 1 : 0;
    if ((tid & 63) == 0 && (b1 | b2)) atomicOr(df, b1 | b2);
    __syncthreads();
    if (tid == 0) flagsArr[bid - 385] = df[0];
    return;
  }
  {
    int gid = (bid - 641) * 256 + tid;
    int b = gid >> 6, c = gid & 63;
    float4 v = ((const float4*)(emb + (size_t)batch[b] * D))[c];
    ((float4*)(X + (size_t)b * D))[c] = v;
    uint2 p;
    p.x = (unsigned)f2bf(v.x) | ((unsigned)f2bf(v.y) << 16);
    p.y = (unsigned)f2bf(v.z) | ((unsigned)f2bf(v.w) << 16);
    ((uint2*)Xb)[gid] = p;
  }
}

// ---------------- bf16 MFMA GEMM, 2-phase pipelined ----------------
// C[M,N] = epi(A[M,K] @ Bt[N,K]^T); A,Bt bf16 row-major. 4 waves as 2x2.
// EPI: 2 acc+bias, 3 relu(acc+bias). OUTBF: bf16 output.
template<int BM, int BN, int EPI, bool OUTBF>
__global__ __launch_bounds__(256) void k_mgemm(const unsigned short* __restrict__ A,
                                               const unsigned short* __restrict__ Bt,
                                               const float* __restrict__ bias,
                                               void* __restrict__ Cout,
                                               int M, int N, int K){
  constexpr int BK = 64;
  constexpr int WM = BM / 2, WN = BN / 2;
  constexpr int MR = WM / 16, NR = WN / 16;
  constexpr int AIT = BM * 8 / 256;   // 16B chunks / 256 threads
  constexpr int BIT = BN * 8 / 256;
  __shared__ __align__(16) unsigned short As[BM * BK];
  __shared__ __align__(16) unsigned short Bs[BN * BK];
  char* ab = (char*)As; char* bb = (char*)Bs;
  const int tid = threadIdx.x;
  const int w = tid >> 6, lane = tid & 63;
  const int wm = w >> 1, wn = w & 1;
  const int row0 = blockIdx.y * BM, col0 = blockIdx.x * BN;
  f32x4 acc[MR][NR];
#pragma unroll
  for (int m = 0; m < MR; m++)
#pragma unroll
    for (int n = 0; n < NR; n++) acc[m][n] = (f32x4){0.f, 0.f, 0.f, 0.f};

  uint4 avr[AIT], bvr[BIT];
  auto load_tiles = [&](int k0){
#pragma unroll
    for (int s = 0; s < AIT; s++){
      int c = s * 256 + tid;
      int r = c >> 3, jj = c & 7;
      avr[s] = *(const uint4*)(A + (size_t)(row0 + r) * K + k0 + jj * 8);
    }
#pragma unroll
    for (int s = 0; s < BIT; s++){
      int c = s * 256 + tid;
      int r = c >> 3, jj = c & 7;
      bvr[s] = *(const uint4*)(Bt + (size_t)(col0 + r) * K + k0 + jj * 8);
    }
  };
  auto store_tiles = [&](){
#pragma unroll
    for (int s = 0; s < AIT; s++){
      int c = s * 256 + tid;
      int r = c >> 3, jj = c & 7;
      *(uint4*)(ab + ESWZ(r, r * 128 + jj * 16)) = avr[s];
    }
#pragma unroll
    for (int s = 0; s < BIT; s++){
      int c = s * 256 + tid;
      int r = c >> 3, jj = c & 7;
      *(uint4*)(bb + ESWZ(r, r * 128 + jj * 16)) = bvr[s];
    }
  };
  auto compute = [&](){
#pragma unroll
    for (int kk = 0; kk < 2; kk++){
      short8 af[MR], bf[NR];
#pragma unroll
      for (int m = 0; m < MR; m++){
        int r = wm * WM + m * 16 + (lane & 15);
        af[m] = *(const short8*)(ab + ESWZ(r, r * 128 + (kk * 4 + (lane >> 4)) * 16));
      }
#pragma unroll
      for (int n = 0; n < NR; n++){
        int r = wn * WN + n * 16 + (lane & 15);
        bf[n] = *(const short8*)(bb + ESWZ(r, r * 128 + (kk * 4 + (lane >> 4)) * 16));
      }
#pragma unroll
      for (int m = 0; m < MR; m++)
#pragma unroll
        for (int n = 0; n < NR; n++)
          acc[m][n] = __builtin_amdgcn_mfma_f32_16x16x32_bf16(af[m], bf[n], acc[m][n], 0, 0, 0);
    }
  };

  load_tiles(0);
  store_tiles();
  __syncthreads();
  for (int k0 = BK; k0 < K; k0 += BK){
    load_tiles(k0);     // next tile -> regs (in flight during compute)
    compute();
    __syncthreads();
    store_tiles();
    __syncthreads();
  }
  compute();

  // epilogue: D row = A-row = (lane>>4)*4+r, D col = B-row = lane&15 (HW-verified r2)
#pragma unroll
  for (int m = 0; m < MR; m++){
#pragma unroll
    for (int n = 0; n < NR; n++){
      int col = col0 + wn * WN + n * 16 + (lane & 15);
      float bsv = bias[col];
      int rbase = row0 + wm * WM + m * 16 + (lane >> 4) * 4;
#pragma unroll
      for (int r = 0; r < 4; r++){
        float v = acc[m][n][r] + bsv;
        if (EPI == 3) v = fmaxf(v, 0.f);
        if (OUTBF) ((unsigned short*)Cout)[(size_t)(rbase + r) * N + col] = f2bf(v);
        else       ((float*)Cout)[(size_t)(rbase + r) * N + col] = v;
      }
    }
  }
}

// ---------------- attention core: 512 threads, 8 waves ----------------
// wave w: stages E rows w*8..+7; scores for l-tile (w&3), k-half (w>>2);
// softmax + PV for head h = w. bf16 P in, bf16 C out (C row aliases P row).
__global__ __launch_bounds__(512) void k_attn(const int* __restrict__ nei_idx,
                                              const void* __restrict__ nei_mask,
                                              const int* __restrict__ flagsArr,
                                              const float* __restrict__ emb,
                                              const unsigned short* __restrict__ Pb,
                                              unsigned short* __restrict__ Cb){
  const int b = blockIdx.x;
  const int tid = threadIdx.x;
  const int w = tid >> 6, lane = tid & 63;
  __shared__ __align__(16) unsigned short Ebf[64 * 256];  // 32 KB, swizzled
  __shared__ __align__(16) unsigned short Pl[9 * 256];    // 4.5 KB, row 8 = zeros
  __shared__ float sc[2 * NH * LN_];                      // 4 KB: [khalf][h][l]
  __shared__ int   nid[LN_];
  __shared__ float mskv[LN_];
  __shared__ int   fred[4];
  char* eb = (char*)Ebf;
  char* pl = (char*)Pl;

  // phase 1: nid, flags OR-reduce, stage P
  if (tid < LN_) nid[tid] = nei_idx[(size_t)b * LN_ + tid];
  if (tid < 256){
    int f = flagsArr[tid];
#pragma unroll
    for (int off = 32; off; off >>= 1) f |= __shfl_xor(f, off, 64);
    if (lane == 0) fred[w] = f;
  }
  if (tid < 256){
    int r = tid >> 5, cb16 = (tid & 31) * 16;
    uint4 v = *(const uint4*)((const char*)Pb + (size_t)b * 4096 + r * 512 + cb16);
    *(uint4*)(pl + ESWZ(r, r * 512 + cb16)) = v;
  }
  if (tid < 64) *(uint2*)(pl + 8 * 512 + tid * 8) = make_uint2(0u, 0u);
  __syncthreads();

  // phase 2: mask load (needs flags), stage E rows (wave w: rows w*8..+7)
  if (tid < LN_){
    int fl = fred[0] | fred[1] | fred[2] | fred[3];
    int mf = (fl & 2) ? 2 : ((fl & 1) ? 1 : 0);
    bool m;
    if (mf == 1)      m = ((const unsigned char*)nei_mask)[(size_t)b * LN_ + tid] != 0;
    else if (mf == 2) m = ((const float*)nei_mask)[(size_t)b * LN_ + tid] != 0.f;
    else              m = ((const int*)nei_mask)[(size_t)b * LN_ + tid] != 0;
    mskv[tid] = m ? 1.f : 0.f;
  }
  {
    float4 vr[8];
#pragma unroll
    for (int i = 0; i < 8; i++){
      int l = w * 8 + i;
      vr[i] = ((const float4*)(emb + (size_t)nid[l] * D))[lane];
    }
#pragma unroll
    for (int i = 0; i < 8; i++){
      int l = w * 8 + i;
      uint2 p;
      p.x = (unsigned)f2bf(vr[i].x) | ((unsigned)f2bf(vr[i].y) << 16);
      p.y = (unsigned)f2bf(vr[i].z) | ((unsigned)f2bf(vr[i].w) << 16);
      *(uint2*)(eb + ESWZ(l, l * 512 + lane * 8)) = p;
    }
  }
  __syncthreads();

  // phase 3: scores^T partial MFMA. wave w: l-tile (w&3), k-half (w>>2) (4 MFMAs)
  {
    const int hr = lane & 15;
    const int arow = hr < 8 ? hr : 8;
    const int bl = (w & 3) * 16 + (lane & 15);
    const int kh = w >> 2;
    const int koff = (lane >> 4) * 16;
    f32x4 acc = {0.f, 0.f, 0.f, 0.f};
#pragma unroll
    for (int kk = 0; kk < 4; kk++){
      int kabs = kh * 4 + kk;
      short8 af = *(const short8*)(pl + ESWZ(arow, arow * 512 + kabs * 64 + koff));
      short8 bf = *(const short8*)(eb + ESWZ(bl, bl * 512 + kabs * 64 + koff));
      acc = __builtin_amdgcn_mfma_f32_16x16x32_bf16(af, bf, acc, 0, 0, 0);
    }
    int hb = (lane >> 4) * 4;
    if (hb < 8){
#pragma unroll
      for (int r = 0; r < 4; r++) sc[kh * 512 + (hb + r) * LN_ + bl] = acc[r];
    }
  }
  __syncthreads();

  // phase 4: softmax. wave w = head w; lane = l (64-wide)
  {
    float v = sc[w * LN_ + lane] + sc[512 + w * LN_ + lane];
    v = mskv[lane] > 0.5f ? -INFINITY : v;
    float m = v;
#pragma unroll
    for (int off = 32; off; off >>= 1) m = fmaxf(m, __shfl_xor(m, off, 64));
    float e = __expf(v - m);
    float s = e;
#pragma unroll
    for (int off = 32; off; off >>= 1) s += __shfl_xor(s, off, 64);
    sc[w * LN_ + lane] = e / s;
  }
  __syncthreads();

  // phase 5: PV. wave w = head w; lane owns d = lane*4..+3; bf16 out
  {
    float4 a0 = make_float4(0.f, 0.f, 0.f, 0.f);
#pragma unroll 8
    for (int l = 0; l < 64; l++){
      uint2 raw = *(const uint2*)(eb + ESWZ(l, l * 512 + lane * 8));
      float t0 = sc[w * LN_ + l];
      a0.x = fmaf(t0, __uint_as_float(raw.x << 16), a0.x);
      a0.y = fmaf(t0, __uint_as_float(raw.x & 0xFFFF0000u), a0.y);
      a0.z = fmaf(t0, __uint_as_float(raw.y << 16), a0.z);
      a0.w = fmaf(t0, __uint_as_float(raw.y & 0xFFFF0000u), a0.w);
    }
    uint2 o0;
    o0.x = (unsigned)f2bf(a0.x) | ((unsigned)f2bf(a0.y) << 16);
    o0.y = (unsigned)f2bf(a0.z) | ((unsigned)f2bf(a0.w) << 16);
    *(uint2*)((char*)Cb + (size_t)b * 4096 + w * 512 + lane * 8) = o0;
  }
}

// ---------------- LayerNorm(out = LN(A+B)), optional bf16 copy ----------------
__global__ __launch_bounds__(256) void k_ln(const float* __restrict__ A,
                                            const float* __restrict__ Bv,
                                            const float* __restrict__ w,
                                            const float* __restrict__ bi,
                                            float* __restrict__ out,
                                            unsigned short* __restrict__ outb){
  const int row = blockIdx.x, tid = threadIdx.x;
  const int wv = tid >> 6, lane = tid & 63;
  __shared__ float red[8];
  float v = A[(size_t)row * D + tid] + Bv[(size_t)row * D + tid];
  float s = wave_sum(v);
  if (lane == 0) red[wv] = s;
  __syncthreads();
  float mu = (red[0] + red[1] + red[2] + red[3]) * (1.f / D);
  float d = v - mu;
  float s2 = wave_sum(d * d);
  if (lane == 0) red[4 + wv] = s2;
  __syncthreads();
  float var = (red[4] + red[5] + red[6] + red[7]) * (1.f / D);
  float res = d * rsqrtf(var + EPSV) * w[tid] + bi[tid];
  out[(size_t)row * D + tid] = res;
  if (outb) outb[(size_t)row * D + tid] = f2bf(res);
}

// ---------------- launch ----------------
extern "C" void kernel_launch(void* const* d_in, const int* in_sizes, int n_in,
                              void* d_out, int out_size, void* d_ws, size_t ws_size,
                              hipStream_t stream){
  (void)in_sizes; (void)n_in; (void)out_size; (void)ws_size;
  const int*   batch    = (const int*)d_in[0];
  const int*   nei_idx  = (const int*)d_in[1];
  const void*  nei_mask = d_in[2];
  const float* emb      = (const float*)d_in[3];
  const float* Wq = (const float*)d_in[4];  const float* bq = (const float*)d_in[5];
  const float* Wk = (const float*)d_in[6];  /* bk dropped: softmax-invariant */
  const float* Wv = (const float*)d_in[8];  const float* bv = (const float*)d_in[9];
  const float* Wo = (const float*)d_in[10]; const float* bo = (const float*)d_in[11];
  const float* W1 = (const float*)d_in[12]; const float* b1 = (const float*)d_in[13];
  const float* W2 = (const float*)d_in[14]; const float* b2 = (const float*)d_in[15];
  const float* ln1w = (const float*)d_in[16]; const float* ln1b = (const float*)d_in[17];
  const float* ln2w = (const float*)d_in[18]; const float* ln2b = (const float*)d_in[19];

  float* ws = (float*)d_ws;
  // 4-MiB slots
  float* X  = ws;                        // slot 0
  float* Y  = ws + (size_t)1 * 1048576;  // slot 1
  float* S  = ws + (size_t)2 * 1048576;  // slot 2
  float* F  = ws + (size_t)3 * 1048576;  // slot 3
  unsigned short* Pbf = (unsigned short*)(ws + (size_t)4 * 1048576);  // slots 4-7 [4096][2048]
  unsigned short* Cb  = Pbf;             // alias: attn block b reads P[b] fully before writing C[b]
  unsigned short* Sb  = (unsigned short*)(ws + (size_t)8 * 1048576);  // slot 8 (2 MB used)
  unsigned short* HHb = (unsigned short*)(ws + (size_t)9 * 1048576);  // slots 9-10 (8 MB)
  unsigned short* Xb  = (unsigned short*)(ws + (size_t)11 * 1048576); // slot 11 (2 MB used)
  char* wb = (char*)(ws + (size_t)12 * 1048576);
  unsigned short* W1t = (unsigned short*)(wb);                        // 512 KiB
  unsigned short* W2t = (unsigned short*)(wb + (512u << 10));         // 512 KiB
  unsigned short* Mt  = (unsigned short*)(wb + (1024u << 10));        // 1 MiB
  unsigned short* Gt  = (unsigned short*)(wb + (2048u << 10));        // 1 MiB
  float* pbv  = (float*)(wb + (3072u << 10));                         // 8 KiB
  float* bo2  = (float*)(wb + (3072u << 10) + 8192);                  // 1 KiB
  int*   flagsArr = (int*)(wb + (3072u << 10) + 16384);               // 256 ints
  float* out = (float*)d_out;

  k_prep<<<1665, 256, 0, stream>>>(Wq, Wk, Wv, Wo, W1, W2, bq, bv, bo,
                                   batch, emb, (const unsigned int*)nei_mask,
                                   W1t, W2t, Mt, Gt, pbv, bo2, X, Xb, flagsArr);
  // P = Xb @ Mt^T + pb  [bf16 out], N=2048
  k_mgemm<128, 64, 2, true><<<dim3(2048 / 64, BQ / 128), 256, 0, stream>>>(Xb, Mt, pbv, Pbf, BQ, 2048, 256);
  k_attn<<<BQ, 512, 0, stream>>>(nei_idx, nei_mask, flagsArr, emb, Pbf, Cb);
  // Y = Cb @ Gt^T + bo2  [f32 out], K=2048
  k_mgemm<64, 64, 2, false><<<dim3(D / 64, BQ / 64), 256, 0, stream>>>(Cb, Gt, bo2, Y, BQ, D, 2048);
  k_ln<<<BQ, 256, 0, stream>>>(X, Y, ln1w, ln1b, S, Sb);
  // HH = relu(S@W1 + b1)  [bf16 out]
  k_mgemm<128, 64, 3, true><<<dim3(DFF / 64, BQ / 128), 256, 0, stream>>>(Sb, W1t, b1, HHb, BQ, DFF, 256);
  // F = relu(HH@W2 + b2)  [f32 out]
  k_mgemm<64, 64, 3, false><<<dim3(D / 64, BQ / 64), 256, 0, stream>>>(HHb, W2t, b2, F, BQ, D, DFF);
  k_ln<<<BQ, 256, 0, stream>>>(S, F, ln2w, ln2b, out, nullptr);
}

// Round 6
// 217.592 us; speedup vs baseline: 1.0423x; 1.0423x over previous
//
#include <hip/hip_runtime.h>
#include <hip/hip_bf16.h>
#include <math.h>

// Problem constants
#define BQ   4096
#define D    256
#define NH   8
#define HD   32
#define LN_  64     // neighbors per node
#define DFF  1024
#define EPSV 1e-5f
#define QSCALE 0.17677669529663687f  // HD^-0.5

typedef __attribute__((ext_vector_type(8))) short short8;
typedef __attribute__((ext_vector_type(4))) float f32x4;

// LDS XOR swizzle (G4): spread 512B/128B-stride rows across banks; bijective involution.
#define ESWZ(row, byte) ((byte) ^ (((row) & 7) << 4))

// ---------------- helpers ----------------
__device__ __forceinline__ float wave_sum(float v){
#pragma unroll
  for (int off = 32; off; off >>= 1) v += __shfl_xor(v, off, 64);
  return v;
}
__device__ __forceinline__ unsigned short f2bf(float f){
  unsigned int u = __float_as_uint(f);
  unsigned int r = (u + 0x7FFFu + ((u >> 16) & 1u)) >> 16;   // RNE
  return (unsigned short)r;
}

// ---------------- mega-prep kernel (block-range dispatch) ----------------
__global__ __launch_bounds__(256) void k_prep(
    const float* __restrict__ Wq, const float* __restrict__ Wk,
    const float* __restrict__ Wv, const float* __restrict__ Wo,
    const float* __restrict__ W1, const float* __restrict__ W2,
    const float* __restrict__ bq, const float* __restrict__ bv,
    const float* __restrict__ bo,
    const int* __restrict__ batch, const float* __restrict__ emb,
    const unsigned int* __restrict__ maskw,
    unsigned short* __restrict__ W1t, unsigned short* __restrict__ W2t,
    unsigned short* __restrict__ Mt, unsigned short* __restrict__ Gt,
    float* __restrict__ pb, float* __restrict__ bo2,
    float* __restrict__ X, unsigned short* __restrict__ Xb,
    int* __restrict__ flagsArr){
  __shared__ float smem[4224];
  const int bid = blockIdx.x;
  const int tid = threadIdx.x;

  if (bid < 128){
    const float* src; unsigned short* dst; int K, N, t0;
    if (bid < 64){ src = W1; dst = W1t; K = 256;  N = 1024; t0 = bid; }
    else         { src = W2; dst = W2t; K = 1024; N = 256;  t0 = bid - 64; }
    const int ntx = N / 64;
    const int k0 = (t0 / ntx) * 64, n0 = (t0 % ntx) * 64;
    float (*Ts)[65] = (float(*)[65])smem;
    {
      int r = tid >> 2, c4 = (tid & 3) * 16;
#pragma unroll
      for (int i = 0; i < 4; i++)
        *(float4*)&Ts[r][c4 + i * 4] = *(const float4*)(src + (size_t)(k0 + r) * N + n0 + c4 + i * 4);
    }
    __syncthreads();
    {
      int n = tid >> 2, kc = (tid & 3) * 16;
      unsigned int pk[8];
#pragma unroll
      for (int i = 0; i < 8; i++){
        unsigned int lo = f2bf(Ts[kc + 2 * i][n]);
        unsigned int hi = f2bf(Ts[kc + 2 * i + 1][n]);
        pk[i] = lo | (hi << 16);
      }
      unsigned short* orow = dst + (size_t)(n0 + n) * K + k0 + kc;
      *(uint4*)(orow)     = *(uint4*)&pk[0];
      *(uint4*)(orow + 8) = *(uint4*)&pk[4];
    }
    return;
  }
  if (bid < 256){
    int t0 = bid - 128;
    int hd0 = (t0 & 31) * 64, c0 = (t0 >> 5) * 64;
    int h = hd0 >> 8, d0 = hd0 & 255;
    float (*WqS)[33] = (float(*)[33])smem;
    float (*WkS)[33] = (float(*)[33])(smem + 64 * 33);
#pragma unroll
    for (int s = 0; s < 2; s++){
      int idx = tid + s * 256;
      int row = idx >> 3, c4 = (idx & 7) * 4;
      *(float4*)&WqS[row][c4] = *(const float4*)(Wq + (size_t)(c0 + row) * 256 + h * 32 + c4);
      *(float4*)&WkS[row][c4] = *(const float4*)(Wk + (size_t)(d0 + row) * 256 + h * 32 + c4);
    }
    __syncthreads();
    int jo = (tid >> 4) * 4, io = (tid & 15) * 4;
    float acc[4][4];
#pragma unroll
    for (int j = 0; j < 4; j++)
#pragma unroll
      for (int i = 0; i < 4; i++) acc[j][i] = 0.f;
#pragma unroll
    for (int t = 0; t < 32; t++){
#pragma unroll
      for (int j = 0; j < 4; j++){
        float kv = WkS[jo + j][t];
#pragma unroll
        for (int i = 0; i < 4; i++) acc[j][i] = fmaf(kv, WqS[io + i][t], acc[j][i]);
      }
    }
#pragma unroll
    for (int j = 0; j < 4; j++){
      uint2 o;
      o.x = (unsigned)f2bf(acc[j][0] * QSCALE) | ((unsigned)f2bf(acc[j][1] * QSCALE) << 16);
      o.y = (unsigned)f2bf(acc[j][2] * QSCALE) | ((unsigned)f2bf(acc[j][3] * QSCALE) << 16);
      *(uint2*)(Mt + (size_t)(hd0 + jo + j) * 256 + c0 + io) = o;
    }
    if (c0 == 0 && tid < 64){
      float s = 0.f;
#pragma unroll
      for (int t = 0; t < 32; t++) s = fmaf(WkS[tid][t], bq[h * 32 + t], s);
      pb[hd0 + tid] = s * QSCALE;
    }
    return;
  }
  if (bid < 384){
    int t0 = bid - 256;
    int hd0 = (t0 & 31) * 64, n0 = (t0 >> 5) * 64;
    int h = hd0 >> 8, d0 = hd0 & 255;
    float (*WvS)[33] = (float(*)[33])smem;
    float (*WoS)[65] = (float(*)[65])(smem + 64 * 33);
#pragma unroll
    for (int s = 0; s < 2; s++){
      int idx = tid + s * 256;
      int row = idx >> 3, c4 = (idx & 7) * 4;
      *(float4*)&WvS[row][c4] = *(const float4*)(Wv + (size_t)(d0 + row) * 256 + h * 32 + c4);
      int row2 = idx >> 4, c42 = (idx & 15) * 4;
      *(float4*)&WoS[row2][c42] = *(const float4*)(Wo + (size_t)(h * 32 + row2) * 256 + n0 + c42);
    }
    __syncthreads();
    int jo = (tid >> 4) * 4, io = (tid & 15) * 4;
    float acc[4][4];
#pragma unroll
    for (int i = 0; i < 4; i++)
#pragma unroll
      for (int j = 0; j < 4; j++) acc[i][j] = 0.f;
#pragma unroll
    for (int t = 0; t < 32; t++){
#pragma unroll
      for (int i = 0; i < 4; i++){
        float ov = WoS[t][io + i];
#pragma unroll
        for (int j = 0; j < 4; j++) acc[i][j] = fmaf(ov, WvS[jo + j][t], acc[i][j]);
      }
    }
#pragma unroll
    for (int i = 0; i < 4; i++){
      uint2 o;
      o.x = (unsigned)f2bf(acc[i][0]) | ((unsigned)f2bf(acc[i][1]) << 16);
      o.y = (unsigned)f2bf(acc[i][2]) | ((unsigned)f2bf(acc[i][3]) << 16);
      *(uint2*)(Gt + (size_t)(n0 + io + i) * 2048 + hd0 + jo) = o;
    }
    return;
  }
  if (bid == 384){
    int n = tid;
    float s = bo[n];
    for (int j = 0; j < 256; j++) s = fmaf(bv[j], Wo[(size_t)j * 256 + n], s);
    bo2[n] = s;
    return;
  }
  if (bid < 641){
    int* df = (int*)smem;
    if (tid == 0) df[0] = 0;
    __syncthreads();
    int idx = (bid - 385) * 256 + tid;
    unsigned int v = maskw[idx];
    int bits = 0;
    if (v == 0x3F800000u) bits = 2;
    else if (v & 0xFFFFFF00u) bits = 1;
    int b2 = __any(bits & 2) ? 2 : 0;
    int b1 = __any(bits & 1) ? 1 : 0;
    if ((tid & 63) == 0 && (b1 | b2)) atomicOr(df, b1 | b2);
    __syncthreads();
    if (tid == 0) flagsArr[bid - 385] = df[0];
    return;
  }
  {
    int gid = (bid - 641) * 256 + tid;
    int b = gid >> 6, c = gid & 63;
    float4 v = ((const float4*)(emb + (size_t)batch[b] * D))[c];
    ((float4*)(X + (size_t)b * D))[c] = v;
    uint2 p;
    p.x = (unsigned)f2bf(v.x) | ((unsigned)f2bf(v.y) << 16);
    p.y = (unsigned)f2bf(v.z) | ((unsigned)f2bf(v.w) << 16);
    ((uint2*)Xb)[gid] = p;
  }
}

// ---------------- bf16 MFMA GEMM, 2-phase pipelined (straight-line, no lambdas) ----------------
// C[M,N] = epi(A[M,K] @ Bt[N,K]^T); A,Bt bf16 row-major. 4 waves as 2x2.
// EPI: 2 acc+bias, 3 relu(acc+bias). OUTBF: bf16 output.
#define MG_LOADA(s, k0) { int c = (s) * 256 + tid; int r = c >> 3, jj = c & 7; \
  avr[s] = *(const uint4*)(A + (size_t)(row0 + r) * K + (k0) + jj * 8); }
#define MG_LOADB(s, k0) { int c = (s) * 256 + tid; int r = c >> 3, jj = c & 7; \
  bvr[s] = *(const uint4*)(Bt + (size_t)(col0 + r) * K + (k0) + jj * 8); }
#define MG_STOREA(s) { int c = (s) * 256 + tid; int r = c >> 3, jj = c & 7; \
  *(uint4*)(ab + ESWZ(r, r * 128 + jj * 16)) = avr[s]; }
#define MG_STOREB(s) { int c = (s) * 256 + tid; int r = c >> 3, jj = c & 7; \
  *(uint4*)(bb + ESWZ(r, r * 128 + jj * 16)) = bvr[s]; }
#define MG_COMPUTE() \
  _Pragma("unroll") \
  for (int kk = 0; kk < 2; kk++){ \
    short8 af[MR], bf[NR]; \
    _Pragma("unroll") \
    for (int m = 0; m < MR; m++){ \
      int r = wm * WM + m * 16 + (lane & 15); \
      af[m] = *(const short8*)(ab + ESWZ(r, r * 128 + (kk * 4 + (lane >> 4)) * 16)); \
    } \
    _Pragma("unroll") \
    for (int n = 0; n < NR; n++){ \
      int r = wn * WN + n * 16 + (lane & 15); \
      bf[n] = *(const short8*)(bb + ESWZ(r, r * 128 + (kk * 4 + (lane >> 4)) * 16)); \
    } \
    _Pragma("unroll") \
    for (int m = 0; m < MR; m++) \
      _Pragma("unroll") \
      for (int n = 0; n < NR; n++) \
        acc[m][n] = __builtin_amdgcn_mfma_f32_16x16x32_bf16(af[m], bf[n], acc[m][n], 0, 0, 0); \
  }

template<int BM, int BN, int EPI, bool OUTBF>
__global__ __launch_bounds__(256) void k_mgemm(const unsigned short* __restrict__ A,
                                               const unsigned short* __restrict__ Bt,
                                               const float* __restrict__ bias,
                                               void* __restrict__ Cout,
                                               int M, int N, int K){
  constexpr int BK = 64;
  constexpr int WM = BM / 2, WN = BN / 2;
  constexpr int MR = WM / 16, NR = WN / 16;
  constexpr int AIT = BM * 8 / 256;   // 16B chunks / 256 threads
  constexpr int BIT = BN * 8 / 256;
  __shared__ __align__(16) unsigned short As[BM * BK];
  __shared__ __align__(16) unsigned short Bs[BN * BK];
  char* ab = (char*)As; char* bb = (char*)Bs;
  const int tid = threadIdx.x;
  const int w = tid >> 6, lane = tid & 63;
  const int wm = w >> 1, wn = w & 1;
  const int row0 = blockIdx.y * BM, col0 = blockIdx.x * BN;
  f32x4 acc[MR][NR];
#pragma unroll
  for (int m = 0; m < MR; m++)
#pragma unroll
    for (int n = 0; n < NR; n++) acc[m][n] = (f32x4){0.f, 0.f, 0.f, 0.f};

  uint4 avr[AIT], bvr[BIT];
  // prologue: tile 0 -> regs -> LDS
#pragma unroll
  for (int s = 0; s < AIT; s++) MG_LOADA(s, 0)
#pragma unroll
  for (int s = 0; s < BIT; s++) MG_LOADB(s, 0)
#pragma unroll
  for (int s = 0; s < AIT; s++) MG_STOREA(s)
#pragma unroll
  for (int s = 0; s < BIT; s++) MG_STOREB(s)
  __syncthreads();
  for (int k0 = BK; k0 < K; k0 += BK){
    // issue next-tile global loads (in flight during compute)
#pragma unroll
    for (int s = 0; s < AIT; s++) MG_LOADA(s, k0)
#pragma unroll
    for (int s = 0; s < BIT; s++) MG_LOADB(s, k0)
    MG_COMPUTE()
    __syncthreads();
#pragma unroll
    for (int s = 0; s < AIT; s++) MG_STOREA(s)
#pragma unroll
    for (int s = 0; s < BIT; s++) MG_STOREB(s)
    __syncthreads();
  }
  MG_COMPUTE()

  // epilogue: D row = A-row = (lane>>4)*4+r, D col = B-row = lane&15 (HW-verified r2)
#pragma unroll
  for (int m = 0; m < MR; m++){
#pragma unroll
    for (int n = 0; n < NR; n++){
      int col = col0 + wn * WN + n * 16 + (lane & 15);
      float bsv = bias[col];
      int rbase = row0 + wm * WM + m * 16 + (lane >> 4) * 4;
#pragma unroll
      for (int r = 0; r < 4; r++){
        float v = acc[m][n][r] + bsv;
        if (EPI == 3) v = fmaxf(v, 0.f);
        if (OUTBF) ((unsigned short*)Cout)[(size_t)(rbase + r) * N + col] = f2bf(v);
        else       ((float*)Cout)[(size_t)(rbase + r) * N + col] = v;
      }
    }
  }
}

// ---------------- attention core: 256 threads, 4 waves (r4 structure + prefetch) ----------------
// wave w: E rows w*16..+15 (global loads issued before P staging); scores via 8-MFMA chain;
// softmax 8x32; PV 2 heads/wave (1 LDS read feeds 8 FMAs). bf16 P in / bf16 C out (C aliases P).
__global__ __launch_bounds__(256) void k_attn(const int* __restrict__ nei_idx,
                                              const void* __restrict__ nei_mask,
                                              const int* __restrict__ flagsArr,
                                              const float* __restrict__ emb,
                                              const unsigned short* __restrict__ Pb,
                                              unsigned short* __restrict__ Cb){
  const int b = blockIdx.x;
  const int tid = threadIdx.x;
  const int w = tid >> 6, lane = tid & 63;
  __shared__ __align__(16) unsigned short Ebf[64 * 256];  // 32 KB, swizzled
  __shared__ __align__(16) unsigned short Pl[9 * 256];    // 4.5 KB, row 8 = zeros
  __shared__ float sc[NH * LN_];                          // 2 KB
  __shared__ float mskv[LN_];
  __shared__ int   fred[4];
  char* eb = (char*)Ebf;
  char* pl = (char*)Pl;

  // flags OR-reduce (one load per thread, wave-OR)
  {
    int f = flagsArr[tid];
#pragma unroll
    for (int off = 32; off; off >>= 1) f |= __shfl_xor(f, off, 64);
    if (lane == 0) fred[w] = f;
  }
  // issue all 16 E-row loads up front (wave-uniform nei_idx reads; latency hides under P staging)
  float4 vr[16];
#pragma unroll
  for (int i = 0; i < 16; i++){
    int nid = nei_idx[(size_t)b * LN_ + w * 16 + i];
    vr[i] = ((const float4*)(emb + (size_t)nid * D))[lane];
  }
  // stage P[b] (bf16) into swizzled LDS; zero pad row 8
  {
    int r = tid >> 5, cb16 = (tid & 31) * 16;
    uint4 v = *(const uint4*)((const char*)Pb + (size_t)b * 4096 + r * 512 + cb16);
    *(uint4*)(pl + ESWZ(r, r * 512 + cb16)) = v;
  }
  if (tid < 64) *(uint2*)(pl + 8 * 512 + tid * 8) = make_uint2(0u, 0u);
  __syncthreads();   // fred ready

  // pack + write E rows to swizzled LDS
#pragma unroll
  for (int i = 0; i < 16; i++){
    int l = w * 16 + i;
    uint2 p;
    p.x = (unsigned)f2bf(vr[i].x) | ((unsigned)f2bf(vr[i].y) << 16);
    p.y = (unsigned)f2bf(vr[i].z) | ((unsigned)f2bf(vr[i].w) << 16);
    *(uint2*)(eb + ESWZ(l, l * 512 + lane * 8)) = p;
  }
  // mask load (needs fred)
  if (tid < LN_){
    int fl = fred[0] | fred[1] | fred[2] | fred[3];
    int mf = (fl & 2) ? 2 : ((fl & 1) ? 1 : 0);
    bool m;
    if (mf == 1)      m = ((const unsigned char*)nei_mask)[(size_t)b * LN_ + tid] != 0;
    else if (mf == 2) m = ((const float*)nei_mask)[(size_t)b * LN_ + tid] != 0.f;
    else              m = ((const int*)nei_mask)[(size_t)b * LN_ + tid] != 0;
    mskv[tid] = m ? 1.f : 0.f;
  }
  __syncthreads();

  // scores^T[h, l] via MFMA chain: A = P rows (8 real + zero pad), B = E rows
  {
    const int hr = lane & 15;
    const int arow = hr < 8 ? hr : 8;
    const int bl = w * 16 + (lane & 15);
    const int koff = (lane >> 4) * 16;
    f32x4 acc = {0.f, 0.f, 0.f, 0.f};
#pragma unroll
    for (int kk = 0; kk < 8; kk++){
      short8 af = *(const short8*)(pl + ESWZ(arow, arow * 512 + kk * 64 + koff));
      short8 bf = *(const short8*)(eb + ESWZ(bl, bl * 512 + kk * 64 + koff));
      acc = __builtin_amdgcn_mfma_f32_16x16x32_bf16(af, bf, acc, 0, 0, 0);
    }
    int hb = (lane >> 4) * 4;
    if (hb < 8){
#pragma unroll
      for (int r = 0; r < 4; r++) sc[(hb + r) * LN_ + bl] = acc[r];
    }
  }
  __syncthreads();

  // softmax: 8 h-groups x 32 threads, each thread covers l = j and j+32
  {
    int h = tid >> 5, j = tid & 31;
    float v0 = mskv[j]      > 0.5f ? -INFINITY : sc[h * LN_ + j];
    float v1 = mskv[j + 32] > 0.5f ? -INFINITY : sc[h * LN_ + j + 32];
    float m = fmaxf(v0, v1);
#pragma unroll
    for (int off = 16; off; off >>= 1) m = fmaxf(m, __shfl_xor(m, off, 64));
    float e0 = __expf(v0 - m), e1 = __expf(v1 - m);
    float s = e0 + e1;
#pragma unroll
    for (int off = 16; off; off >>= 1) s += __shfl_xor(s, off, 64);
    float inv = 1.f / s;
    sc[h * LN_ + j]      = e0 * inv;
    sc[h * LN_ + j + 32] = e1 * inv;
  }
  __syncthreads();

  // PV: wave w computes heads {2w, 2w+1}; lane owns d = lane*4..+3; bf16 out
  {
    const int h0 = w * 2, h1 = w * 2 + 1;
    float4 a0 = make_float4(0.f, 0.f, 0.f, 0.f);
    float4 a1 = make_float4(0.f, 0.f, 0.f, 0.f);
#pragma unroll 8
    for (int l = 0; l < 64; l++){
      uint2 raw = *(const uint2*)(eb + ESWZ(l, l * 512 + lane * 8));
      float e0 = __uint_as_float(raw.x << 16);
      float e1 = __uint_as_float(raw.x & 0xFFFF0000u);
      float e2 = __uint_as_float(raw.y << 16);
      float e3 = __uint_as_float(raw.y & 0xFFFF0000u);
      float t0 = sc[h0 * LN_ + l], t1 = sc[h1 * LN_ + l];
      a0.x = fmaf(t0, e0, a0.x); a0.y = fmaf(t0, e1, a0.y);
      a0.z = fmaf(t0, e2, a0.z); a0.w = fmaf(t0, e3, a0.w);
      a1.x = fmaf(t1, e0, a1.x); a1.y = fmaf(t1, e1, a1.y);
      a1.z = fmaf(t1, e2, a1.z); a1.w = fmaf(t1, e3, a1.w);
    }
    uint2 o0, o1;
    o0.x = (unsigned)f2bf(a0.x) | ((unsigned)f2bf(a0.y) << 16);
    o0.y = (unsigned)f2bf(a0.z) | ((unsigned)f2bf(a0.w) << 16);
    o1.x = (unsigned)f2bf(a1.x) | ((unsigned)f2bf(a1.y) << 16);
    o1.y = (unsigned)f2bf(a1.z) | ((unsigned)f2bf(a1.w) << 16);
    *(uint2*)((char*)Cb + (size_t)b * 4096 + h0 * 512 + lane * 8) = o0;
    *(uint2*)((char*)Cb + (size_t)b * 4096 + h1 * 512 + lane * 8) = o1;
  }
}

// ---------------- LayerNorm(out = LN(A+B)), optional bf16 copy ----------------
__global__ __launch_bounds__(256) void k_ln(const float* __restrict__ A,
                                            const float* __restrict__ Bv,
                                            const float* __restrict__ w,
                                            const float* __restrict__ bi,
                                            float* __restrict__ out,
                                            unsigned short* __restrict__ outb){
  const int row = blockIdx.x, tid = threadIdx.x;
  const int wv = tid >> 6, lane = tid & 63;
  __shared__ float red[8];
  float v = A[(size_t)row * D + tid] + Bv[(size_t)row * D + tid];
  float s = wave_sum(v);
  if (lane == 0) red[wv] = s;
  __syncthreads();
  float mu = (red[0] + red[1] + red[2] + red[3]) * (1.f / D);
  float d = v - mu;
  float s2 = wave_sum(d * d);
  if (lane == 0) red[4 + wv] = s2;
  __syncthreads();
  float var = (red[4] + red[5] + red[6] + red[7]) * (1.f / D);
  float res = d * rsqrtf(var + EPSV) * w[tid] + bi[tid];
  out[(size_t)row * D + tid] = res;
  if (outb) outb[(size_t)row * D + tid] = f2bf(res);
}

// ---------------- launch ----------------
extern "C" void kernel_launch(void* const* d_in, const int* in_sizes, int n_in,
                              void* d_out, int out_size, void* d_ws, size_t ws_size,
                              hipStream_t stream){
  (void)in_sizes; (void)n_in; (void)out_size; (void)ws_size;
  const int*   batch    = (const int*)d_in[0];
  const int*   nei_idx  = (const int*)d_in[1];
  const void*  nei_mask = d_in[2];
  const float* emb      = (const float*)d_in[3];
  const float* Wq = (const float*)d_in[4];  const float* bq = (const float*)d_in[5];
  const float* Wk = (const float*)d_in[6];  /* bk dropped: softmax-invariant */
  const float* Wv = (const float*)d_in[8];  const float* bv = (const float*)d_in[9];
  const float* Wo = (const float*)d_in[10]; const float* bo = (const float*)d_in[11];
  const float* W1 = (const float*)d_in[12]; const float* b1 = (const float*)d_in[13];
  const float* W2 = (const float*)d_in[14]; const float* b2 = (const float*)d_in[15];
  const float* ln1w = (const float*)d_in[16]; const float* ln1b = (const float*)d_in[17];
  const float* ln2w = (const float*)d_in[18]; const float* ln2b = (const float*)d_in[19];

  float* ws = (float*)d_ws;
  // 4-MiB slots
  float* X  = ws;                        // slot 0
  float* Y  = ws + (size_t)1 * 1048576;  // slot 1
  float* S  = ws + (size_t)2 * 1048576;  // slot 2
  float* F  = ws + (size_t)3 * 1048576;  // slot 3
  unsigned short* Pbf = (unsigned short*)(ws + (size_t)4 * 1048576);  // slots 4-7 [4096][2048]
  unsigned short* Cb  = Pbf;             // alias: attn block b reads P[b] fully before writing C[b]
  unsigned short* Sb  = (unsigned short*)(ws + (size_t)8 * 1048576);  // slot 8 (2 MB used)
  unsigned short* HHb = (unsigned short*)(ws + (size_t)9 * 1048576);  // slots 9-10 (8 MB)
  unsigned short* Xb  = (unsigned short*)(ws + (size_t)11 * 1048576); // slot 11 (2 MB used)
  char* wb = (char*)(ws + (size_t)12 * 1048576);
  unsigned short* W1t = (unsigned short*)(wb);                        // 512 KiB
  unsigned short* W2t = (unsigned short*)(wb + (512u << 10));         // 512 KiB
  unsigned short* Mt  = (unsigned short*)(wb + (1024u << 10));        // 1 MiB
  unsigned short* Gt  = (unsigned short*)(wb + (2048u << 10));        // 1 MiB
  float* pbv  = (float*)(wb + (3072u << 10));                         // 8 KiB
  float* bo2  = (float*)(wb + (3072u << 10) + 8192);                  // 1 KiB
  int*   flagsArr = (int*)(wb + (3072u << 10) + 16384);               // 256 ints
  float* out = (float*)d_out;

  k_prep<<<1665, 256, 0, stream>>>(Wq, Wk, Wv, Wo, W1, W2, bq, bv, bo,
                                   batch, emb, (const unsigned int*)nei_mask,
                                   W1t, W2t, Mt, Gt, pbv, bo2, X, Xb, flagsArr);
  // P = Xb @ Mt^T + pb  [bf16 out], N=2048
  k_mgemm<128, 64, 2, true><<<dim3(2048 / 64, BQ / 128), 256, 0, stream>>>(Xb, Mt, pbv, Pbf, BQ, 2048, 256);
  k_attn<<<BQ, 256, 0, stream>>>(nei_idx, nei_mask, flagsArr, emb, Pbf, Cb);
  // Y = Cb @ Gt^T + bo2  [f32 out], K=2048
  k_mgemm<64, 64, 2, false><<<dim3(D / 64, BQ / 64), 256, 0, stream>>>(Cb, Gt, bo2, Y, BQ, D, 2048);
  k_ln<<<BQ, 256, 0, stream>>>(X, Y, ln1w, ln1b, S, Sb);
  // HH = relu(S@W1 + b1)  [bf16 out]
  k_mgemm<128, 64, 3, true><<<dim3(DFF / 64, BQ / 128), 256, 0, stream>>>(Sb, W1t, b1, HHb, BQ, DFF, 256);
  // F = relu(HH@W2 + b2)  [f32 out]
  k_mgemm<64, 64, 3, false><<<dim3(D / 64, BQ / 64), 256, 0, stream>>>(HHb, W2t, b2, F, BQ, D, DFF);
  k_ln<<<BQ, 256, 0, stream>>>(S, F, ln2w, ln2b, out, nullptr);
}

// Round 7
// 122.305 us; speedup vs baseline: 1.8543x; 1.7791x over previous
//
#include <hip/hip_runtime.h>
#include <hip/hip_bf16.h>
#include <math.h>

// Problem constants
#define BQ   4096
#define D    256
#define NH   8
#define HD   32
#define LN_  64     // neighbors per node
#define DFF  1024
#define EPSV 1e-5f
#define QSCALE 0.17677669529663687f  // HD^-0.5

typedef __attribute__((ext_vector_type(8))) short short8;
typedef __attribute__((ext_vector_type(4))) float f32x4;

// LDS XOR swizzle (G4): spread 512B/128B-stride rows across banks; bijective involution.
#define ESWZ(row, byte) ((byte) ^ (((row) & 7) << 4))

// ---------------- helpers ----------------
__device__ __forceinline__ float wave_sum(float v){
#pragma unroll
  for (int off = 32; off; off >>= 1) v += __shfl_xor(v, off, 64);
  return v;
}
__device__ __forceinline__ unsigned short f2bf(float f){
  unsigned int u = __float_as_uint(f);
  unsigned int r = (u + 0x7FFFu + ((u >> 16) & 1u)) >> 16;   // RNE
  return (unsigned short)r;
}

// ---------------- mega-prep kernel (block-range dispatch) ----------------
__global__ __launch_bounds__(256) void k_prep(
    const float* __restrict__ Wq, const float* __restrict__ Wk,
    const float* __restrict__ Wv, const float* __restrict__ Wo,
    const float* __restrict__ W1, const float* __restrict__ W2,
    const float* __restrict__ bq, const float* __restrict__ bv,
    const float* __restrict__ bo,
    const int* __restrict__ batch, const float* __restrict__ emb,
    const unsigned int* __restrict__ maskw,
    unsigned short* __restrict__ W1t, unsigned short* __restrict__ W2t,
    unsigned short* __restrict__ Mt, unsigned short* __restrict__ Gt,
    float* __restrict__ pb, float* __restrict__ bo2,
    float* __restrict__ X, unsigned short* __restrict__ Xb,
    int* __restrict__ flagsArr){
  __shared__ float smem[4224];
  const int bid = blockIdx.x;
  const int tid = threadIdx.x;

  if (bid < 128){
    const float* src; unsigned short* dst; int K, N, t0;
    if (bid < 64){ src = W1; dst = W1t; K = 256;  N = 1024; t0 = bid; }
    else         { src = W2; dst = W2t; K = 1024; N = 256;  t0 = bid - 64; }
    const int ntx = N / 64;
    const int k0 = (t0 / ntx) * 64, n0 = (t0 % ntx) * 64;
    float (*Ts)[65] = (float(*)[65])smem;
    {
      int r = tid >> 2, c4 = (tid & 3) * 16;
#pragma unroll
      for (int i = 0; i < 4; i++)
        *(float4*)&Ts[r][c4 + i * 4] = *(const float4*)(src + (size_t)(k0 + r) * N + n0 + c4 + i * 4);
    }
    __syncthreads();
    {
      int n = tid >> 2, kc = (tid & 3) * 16;
      unsigned int pk[8];
#pragma unroll
      for (int i = 0; i < 8; i++){
        unsigned int lo = f2bf(Ts[kc + 2 * i][n]);
        unsigned int hi = f2bf(Ts[kc + 2 * i + 1][n]);
        pk[i] = lo | (hi << 16);
      }
      unsigned short* orow = dst + (size_t)(n0 + n) * K + k0 + kc;
      *(uint4*)(orow)     = *(uint4*)&pk[0];
      *(uint4*)(orow + 8) = *(uint4*)&pk[4];
    }
    return;
  }
  if (bid < 256){
    int t0 = bid - 128;
    int hd0 = (t0 & 31) * 64, c0 = (t0 >> 5) * 64;
    int h = hd0 >> 8, d0 = hd0 & 255;
    float (*WqS)[33] = (float(*)[33])smem;
    float (*WkS)[33] = (float(*)[33])(smem + 64 * 33);
#pragma unroll
    for (int s = 0; s < 2; s++){
      int idx = tid + s * 256;
      int row = idx >> 3, c4 = (idx & 7) * 4;
      *(float4*)&WqS[row][c4] = *(const float4*)(Wq + (size_t)(c0 + row) * 256 + h * 32 + c4);
      *(float4*)&WkS[row][c4] = *(const float4*)(Wk + (size_t)(d0 + row) * 256 + h * 32 + c4);
    }
    __syncthreads();
    int jo = (tid >> 4) * 4, io = (tid & 15) * 4;
    float acc[4][4];
#pragma unroll
    for (int j = 0; j < 4; j++)
#pragma unroll
      for (int i = 0; i < 4; i++) acc[j][i] = 0.f;
#pragma unroll
    for (int t = 0; t < 32; t++){
#pragma unroll
      for (int j = 0; j < 4; j++){
        float kv = WkS[jo + j][t];
#pragma unroll
        for (int i = 0; i < 4; i++) acc[j][i] = fmaf(kv, WqS[io + i][t], acc[j][i]);
      }
    }
#pragma unroll
    for (int j = 0; j < 4; j++){
      uint2 o;
      o.x = (unsigned)f2bf(acc[j][0] * QSCALE) | ((unsigned)f2bf(acc[j][1] * QSCALE) << 16);
      o.y = (unsigned)f2bf(acc[j][2] * QSCALE) | ((unsigned)f2bf(acc[j][3] * QSCALE) << 16);
      *(uint2*)(Mt + (size_t)(hd0 + jo + j) * 256 + c0 + io) = o;
    }
    if (c0 == 0 && tid < 64){
      float s = 0.f;
#pragma unroll
      for (int t = 0; t < 32; t++) s = fmaf(WkS[tid][t], bq[h * 32 + t], s);
      pb[hd0 + tid] = s * QSCALE;
    }
    return;
  }
  if (bid < 384){
    int t0 = bid - 256;
    int hd0 = (t0 & 31) * 64, n0 = (t0 >> 5) * 64;
    int h = hd0 >> 8, d0 = hd0 & 255;
    float (*WvS)[33] = (float(*)[33])smem;
    float (*WoS)[65] = (float(*)[65])(smem + 64 * 33);
#pragma unroll
    for (int s = 0; s < 2; s++){
      int idx = tid + s * 256;
      int row = idx >> 3, c4 = (idx & 7) * 4;
      *(float4*)&WvS[row][c4] = *(const float4*)(Wv + (size_t)(d0 + row) * 256 + h * 32 + c4);
      int row2 = idx >> 4, c42 = (idx & 15) * 4;
      *(float4*)&WoS[row2][c42] = *(const float4*)(Wo + (size_t)(h * 32 + row2) * 256 + n0 + c42);
    }
    __syncthreads();
    int jo = (tid >> 4) * 4, io = (tid & 15) * 4;
    float acc[4][4];
#pragma unroll
    for (int i = 0; i < 4; i++)
#pragma unroll
      for (int j = 0; j < 4; j++) acc[i][j] = 0.f;
#pragma unroll
    for (int t = 0; t < 32; t++){
#pragma unroll
      for (int i = 0; i < 4; i++){
        float ov = WoS[t][io + i];
#pragma unroll
        for (int j = 0; j < 4; j++) acc[i][j] = fmaf(ov, WvS[jo + j][t], acc[i][j]);
      }
    }
#pragma unroll
    for (int i = 0; i < 4; i++){
      uint2 o;
      o.x = (unsigned)f2bf(acc[i][0]) | ((unsigned)f2bf(acc[i][1]) << 16);
      o.y = (unsigned)f2bf(acc[i][2]) | ((unsigned)f2bf(acc[i][3]) << 16);
      *(uint2*)(Gt + (size_t)(n0 + io + i) * 2048 + hd0 + jo) = o;
    }
    return;
  }
  if (bid == 384){
    int n = tid;
    float s = bo[n];
    for (int j = 0; j < 256; j++) s = fmaf(bv[j], Wo[(size_t)j * 256 + n], s);
    bo2[n] = s;
    return;
  }
  if (bid < 641){
    int* df = (int*)smem;
    if (tid == 0) df[0] = 0;
    __syncthreads();
    int idx = (bid - 385) * 256 + tid;
    unsigned int v = maskw[idx];
    int bits = 0;
    if (v == 0x3F800000u) bits = 2;
    else if (v & 0xFFFFFF00u) bits = 1;
    int b2 = __any(bits & 2) ? 2 : 0;
    int b1 = __any(bits & 1) ? 1 : 0;
    if ((tid & 63) == 0 && (b1 | b2)) atomicOr(df, b1 | b2);
    __syncthreads();
    if (tid == 0) flagsArr[bid - 385] = df[0];
    return;
  }
  {
    int gid = (bid - 641) * 256 + tid;
    int b = gid >> 6, c = gid & 63;
    float4 v = ((const float4*)(emb + (size_t)batch[b] * D))[c];
    ((float4*)(X + (size_t)b * D))[c] = v;
    uint2 p;
    p.x = (unsigned)f2bf(v.x) | ((unsigned)f2bf(v.y) << 16);
    p.y = (unsigned)f2bf(v.z) | ((unsigned)f2bf(v.w) << 16);
    ((uint2*)Xb)[gid] = p;
  }
}

// ---------------- bf16 MFMA GEMM (r4 body: direct staging, no reg pipeline) ----------------
// C[M,N] = epi(A[M,K] @ Bt[N,K]^T); A,Bt bf16 row-major. 4 waves as 2x2.
// XCD-aware block swizzle (T1/m204): requires nwg % 8 == 0 (all our grids).
// EPI: 2 acc+bias, 3 relu(acc+bias). OUTBF: bf16 output.
template<int BM, int BN, int EPI, bool OUTBF>
__global__ __launch_bounds__(256) void k_mgemm(const unsigned short* __restrict__ A,
                                               const unsigned short* __restrict__ Bt,
                                               const float* __restrict__ bias,
                                               void* __restrict__ Cout,
                                               int M, int N, int K){
  constexpr int BK = 64;
  constexpr int WM = BM / 2, WN = BN / 2;
  constexpr int MR = WM / 16, NR = WN / 16;
  constexpr int AIT = BM * 8 / 256;   // 16B chunks / 256 threads
  constexpr int BIT = BN * 8 / 256;
  __shared__ __align__(16) unsigned short As[BM * BK];
  __shared__ __align__(16) unsigned short Bs[BN * BK];
  char* ab = (char*)As; char* bb = (char*)Bs;
  const int tid = threadIdx.x;
  const int w = tid >> 6, lane = tid & 63;
  const int wm = w >> 1, wn = w & 1;
  // XCD swizzle: hardware id o (round-robins XCDs) -> logical lin; each XCD gets
  // a contiguous chunk of row-panels for L2 locality.
  const int gx = gridDim.x;
  const int nwg = gx * gridDim.y;
  const int o = blockIdx.y * gx + blockIdx.x;
  const int lin = (o & 7) * (nwg >> 3) + (o >> 3);
  const int row0 = (lin / gx) * BM, col0 = (lin % gx) * BN;
  f32x4 acc[MR][NR];
#pragma unroll
  for (int m = 0; m < MR; m++)
#pragma unroll
    for (int n = 0; n < NR; n++) acc[m][n] = (f32x4){0.f, 0.f, 0.f, 0.f};

  for (int k0 = 0; k0 < K; k0 += BK){
#pragma unroll
    for (int s = 0; s < AIT; s++){
      int c = s * 256 + tid;
      int r = c >> 3, jj = c & 7;
      uint4 v = *(const uint4*)(A + (size_t)(row0 + r) * K + k0 + jj * 8);
      *(uint4*)(ab + ESWZ(r, r * 128 + jj * 16)) = v;
    }
#pragma unroll
    for (int s = 0; s < BIT; s++){
      int c = s * 256 + tid;
      int r = c >> 3, jj = c & 7;
      uint4 v = *(const uint4*)(Bt + (size_t)(col0 + r) * K + k0 + jj * 8);
      *(uint4*)(bb + ESWZ(r, r * 128 + jj * 16)) = v;
    }
    __syncthreads();
#pragma unroll
    for (int kk = 0; kk < 2; kk++){
      short8 af[MR], bf[NR];
#pragma unroll
      for (int m = 0; m < MR; m++){
        int r = wm * WM + m * 16 + (lane & 15);
        af[m] = *(const short8*)(ab + ESWZ(r, r * 128 + (kk * 4 + (lane >> 4)) * 16));
      }
#pragma unroll
      for (int n = 0; n < NR; n++){
        int r = wn * WN + n * 16 + (lane & 15);
        bf[n] = *(const short8*)(bb + ESWZ(r, r * 128 + (kk * 4 + (lane >> 4)) * 16));
      }
#pragma unroll
      for (int m = 0; m < MR; m++)
#pragma unroll
        for (int n = 0; n < NR; n++)
          acc[m][n] = __builtin_amdgcn_mfma_f32_16x16x32_bf16(af[m], bf[n], acc[m][n], 0, 0, 0);
    }
    __syncthreads();
  }
  // epilogue: D row = A-row = (lane>>4)*4+r, D col = B-row = lane&15 (HW-verified r2)
#pragma unroll
  for (int m = 0; m < MR; m++){
#pragma unroll
    for (int n = 0; n < NR; n++){
      int col = col0 + wn * WN + n * 16 + (lane & 15);
      float bsv = bias[col];
      int rbase = row0 + wm * WM + m * 16 + (lane >> 4) * 4;
#pragma unroll
      for (int r = 0; r < 4; r++){
        float v = acc[m][n][r] + bsv;
        if (EPI == 3) v = fmaxf(v, 0.f);
        if (OUTBF) ((unsigned short*)Cout)[(size_t)(rbase + r) * N + col] = f2bf(v);
        else       ((float*)Cout)[(size_t)(rbase + r) * N + col] = v;
      }
    }
  }
}

// ---------------- attention core: 256 threads, 4 waves (r6 structure) ----------------
__global__ __launch_bounds__(256) void k_attn(const int* __restrict__ nei_idx,
                                              const void* __restrict__ nei_mask,
                                              const int* __restrict__ flagsArr,
                                              const float* __restrict__ emb,
                                              const unsigned short* __restrict__ Pb,
                                              unsigned short* __restrict__ Cb){
  const int b = blockIdx.x;
  const int tid = threadIdx.x;
  const int w = tid >> 6, lane = tid & 63;
  __shared__ __align__(16) unsigned short Ebf[64 * 256];  // 32 KB, swizzled
  __shared__ __align__(16) unsigned short Pl[9 * 256];    // 4.5 KB, row 8 = zeros
  __shared__ float sc[NH * LN_];                          // 2 KB
  __shared__ float mskv[LN_];
  __shared__ int   fred[4];
  char* eb = (char*)Ebf;
  char* pl = (char*)Pl;

  // flags OR-reduce
  {
    int f = flagsArr[tid];
#pragma unroll
    for (int off = 32; off; off >>= 1) f |= __shfl_xor(f, off, 64);
    if (lane == 0) fred[w] = f;
  }
  // issue all 16 E-row loads up front (latency hides under P staging)
  float4 vr[16];
#pragma unroll
  for (int i = 0; i < 16; i++){
    int nid = nei_idx[(size_t)b * LN_ + w * 16 + i];
    vr[i] = ((const float4*)(emb + (size_t)nid * D))[lane];
  }
  // stage P[b] (bf16) into swizzled LDS; zero pad row 8
  {
    int r = tid >> 5, cb16 = (tid & 31) * 16;
    uint4 v = *(const uint4*)((const char*)Pb + (size_t)b * 4096 + r * 512 + cb16);
    *(uint4*)(pl + ESWZ(r, r * 512 + cb16)) = v;
  }
  if (tid < 64) *(uint2*)(pl + 8 * 512 + tid * 8) = make_uint2(0u, 0u);
  __syncthreads();   // fred ready

  // pack + write E rows to swizzled LDS
#pragma unroll
  for (int i = 0; i < 16; i++){
    int l = w * 16 + i;
    uint2 p;
    p.x = (unsigned)f2bf(vr[i].x) | ((unsigned)f2bf(vr[i].y) << 16);
    p.y = (unsigned)f2bf(vr[i].z) | ((unsigned)f2bf(vr[i].w) << 16);
    *(uint2*)(eb + ESWZ(l, l * 512 + lane * 8)) = p;
  }
  // mask load (needs fred)
  if (tid < LN_){
    int fl = fred[0] | fred[1] | fred[2] | fred[3];
    int mf = (fl & 2) ? 2 : ((fl & 1) ? 1 : 0);
    bool m;
    if (mf == 1)      m = ((const unsigned char*)nei_mask)[(size_t)b * LN_ + tid] != 0;
    else if (mf == 2) m = ((const float*)nei_mask)[(size_t)b * LN_ + tid] != 0.f;
    else              m = ((const int*)nei_mask)[(size_t)b * LN_ + tid] != 0;
    mskv[tid] = m ? 1.f : 0.f;
  }
  __syncthreads();

  // scores^T[h, l] via MFMA chain: A = P rows (8 real + zero pad), B = E rows
  {
    const int hr = lane & 15;
    const int arow = hr < 8 ? hr : 8;
    const int bl = w * 16 + (lane & 15);
    const int koff = (lane >> 4) * 16;
    f32x4 acc = {0.f, 0.f, 0.f, 0.f};
#pragma unroll
    for (int kk = 0; kk < 8; kk++){
      short8 af = *(const short8*)(pl + ESWZ(arow, arow * 512 + kk * 64 + koff));
      short8 bf = *(const short8*)(eb + ESWZ(bl, bl * 512 + kk * 64 + koff));
      acc = __builtin_amdgcn_mfma_f32_16x16x32_bf16(af, bf, acc, 0, 0, 0);
    }
    int hb = (lane >> 4) * 4;
    if (hb < 8){
#pragma unroll
      for (int r = 0; r < 4; r++) sc[(hb + r) * LN_ + bl] = acc[r];
    }
  }
  __syncthreads();

  // softmax: 8 h-groups x 32 threads, each thread covers l = j and j+32
  {
    int h = tid >> 5, j = tid & 31;
    float v0 = mskv[j]      > 0.5f ? -INFINITY : sc[h * LN_ + j];
    float v1 = mskv[j + 32] > 0.5f ? -INFINITY : sc[h * LN_ + j + 32];
    float m = fmaxf(v0, v1);
#pragma unroll
    for (int off = 16; off; off >>= 1) m = fmaxf(m, __shfl_xor(m, off, 64));
    float e0 = __expf(v0 - m), e1 = __expf(v1 - m);
    float s = e0 + e1;
#pragma unroll
    for (int off = 16; off; off >>= 1) s += __shfl_xor(s, off, 64);
    float inv = 1.f / s;
    sc[h * LN_ + j]      = e0 * inv;
    sc[h * LN_ + j + 32] = e1 * inv;
  }
  __syncthreads();

  // PV: wave w computes heads {2w, 2w+1}; lane owns d = lane*4..+3; bf16 out
  {
    const int h0 = w * 2, h1 = w * 2 + 1;
    float4 a0 = make_float4(0.f, 0.f, 0.f, 0.f);
    float4 a1 = make_float4(0.f, 0.f, 0.f, 0.f);
#pragma unroll 8
    for (int l = 0; l < 64; l++){
      uint2 raw = *(const uint2*)(eb + ESWZ(l, l * 512 + lane * 8));
      float e0 = __uint_as_float(raw.x << 16);
      float e1 = __uint_as_float(raw.x & 0xFFFF0000u);
      float e2 = __uint_as_float(raw.y << 16);
      float e3 = __uint_as_float(raw.y & 0xFFFF0000u);
      float t0 = sc[h0 * LN_ + l], t1 = sc[h1 * LN_ + l];
      a0.x = fmaf(t0, e0, a0.x); a0.y = fmaf(t0, e1, a0.y);
      a0.z = fmaf(t0, e2, a0.z); a0.w = fmaf(t0, e3, a0.w);
      a1.x = fmaf(t1, e0, a1.x); a1.y = fmaf(t1, e1, a1.y);
      a1.z = fmaf(t1, e2, a1.z); a1.w = fmaf(t1, e3, a1.w);
    }
    uint2 o0, o1;
    o0.x = (unsigned)f2bf(a0.x) | ((unsigned)f2bf(a0.y) << 16);
    o0.y = (unsigned)f2bf(a0.z) | ((unsigned)f2bf(a0.w) << 16);
    o1.x = (unsigned)f2bf(a1.x) | ((unsigned)f2bf(a1.y) << 16);
    o1.y = (unsigned)f2bf(a1.z) | ((unsigned)f2bf(a1.w) << 16);
    *(uint2*)((char*)Cb + (size_t)b * 4096 + h0 * 512 + lane * 8) = o0;
    *(uint2*)((char*)Cb + (size_t)b * 4096 + h1 * 512 + lane * 8) = o1;
  }
}

// ---------------- LayerNorm(out = LN(A+B)), optional bf16 copy ----------------
__global__ __launch_bounds__(256) void k_ln(const float* __restrict__ A,
                                            const float* __restrict__ Bv,
                                            const float* __restrict__ w,
                                            const float* __restrict__ bi,
                                            float* __restrict__ out,
                                            unsigned short* __restrict__ outb){
  const int row = blockIdx.x, tid = threadIdx.x;
  const int wv = tid >> 6, lane = tid & 63;
  __shared__ float red[8];
  float v = A[(size_t)row * D + tid] + Bv[(size_t)row * D + tid];
  float s = wave_sum(v);
  if (lane == 0) red[wv] = s;
  __syncthreads();
  float mu = (red[0] + red[1] + red[2] + red[3]) * (1.f / D);
  float d = v - mu;
  float s2 = wave_sum(d * d);
  if (lane == 0) red[4 + wv] = s2;
  __syncthreads();
  float var = (red[4] + red[5] + red[6] + red[7]) * (1.f / D);
  float res = d * rsqrtf(var + EPSV) * w[tid] + bi[tid];
  out[(size_t)row * D + tid] = res;
  if (outb) outb[(size_t)row * D + tid] = f2bf(res);
}

// ---------------- launch ----------------
extern "C" void kernel_launch(void* const* d_in, const int* in_sizes, int n_in,
                              void* d_out, int out_size, void* d_ws, size_t ws_size,
                              hipStream_t stream){
  (void)in_sizes; (void)n_in; (void)out_size; (void)ws_size;
  const int*   batch    = (const int*)d_in[0];
  const int*   nei_idx  = (const int*)d_in[1];
  const void*  nei_mask = d_in[2];
  const float* emb      = (const float*)d_in[3];
  const float* Wq = (const float*)d_in[4];  const float* bq = (const float*)d_in[5];
  const float* Wk = (const float*)d_in[6];  /* bk dropped: softmax-invariant */
  const float* Wv = (const float*)d_in[8];  const float* bv = (const float*)d_in[9];
  const float* Wo = (const float*)d_in[10]; const float* bo = (const float*)d_in[11];
  const float* W1 = (const float*)d_in[12]; const float* b1 = (const float*)d_in[13];
  const float* W2 = (const float*)d_in[14]; const float* b2 = (const float*)d_in[15];
  const float* ln1w = (const float*)d_in[16]; const float* ln1b = (const float*)d_in[17];
  const float* ln2w = (const float*)d_in[18]; const float* ln2b = (const float*)d_in[19];

  float* ws = (float*)d_ws;
  // 4-MiB slots
  float* X  = ws;                        // slot 0
  float* Y  = ws + (size_t)1 * 1048576;  // slot 1
  float* S  = ws + (size_t)2 * 1048576;  // slot 2
  float* F  = ws + (size_t)3 * 1048576;  // slot 3
  unsigned short* Pbf = (unsigned short*)(ws + (size_t)4 * 1048576);  // slots 4-7 [4096][2048]
  unsigned short* Cb  = Pbf;             // alias: attn block b reads P[b] fully before writing C[b]
  unsigned short* Sb  = (unsigned short*)(ws + (size_t)8 * 1048576);  // slot 8 (2 MB used)
  unsigned short* HHb = (unsigned short*)(ws + (size_t)9 * 1048576);  // slots 9-10 (8 MB)
  unsigned short* Xb  = (unsigned short*)(ws + (size_t)11 * 1048576); // slot 11 (2 MB used)
  char* wb = (char*)(ws + (size_t)12 * 1048576);
  unsigned short* W1t = (unsigned short*)(wb);                        // 512 KiB
  unsigned short* W2t = (unsigned short*)(wb + (512u << 10));         // 512 KiB
  unsigned short* Mt  = (unsigned short*)(wb + (1024u << 10));        // 1 MiB
  unsigned short* Gt  = (unsigned short*)(wb + (2048u << 10));        // 1 MiB
  float* pbv  = (float*)(wb + (3072u << 10));                         // 8 KiB
  float* bo2  = (float*)(wb + (3072u << 10) + 8192);                  // 1 KiB
  int*   flagsArr = (int*)(wb + (3072u << 10) + 16384);               // 256 ints
  float* out = (float*)d_out;

  k_prep<<<1665, 256, 0, stream>>>(Wq, Wk, Wv, Wo, W1, W2, bq, bv, bo,
                                   batch, emb, (const unsigned int*)nei_mask,
                                   W1t, W2t, Mt, Gt, pbv, bo2, X, Xb, flagsArr);
  // P = Xb @ Mt^T + pb  [bf16 out], N=2048; grid 1024 blocks
  k_mgemm<128, 64, 2, true><<<dim3(2048 / 64, BQ / 128), 256, 0, stream>>>(Xb, Mt, pbv, Pbf, BQ, 2048, 256);
  k_attn<<<BQ, 256, 0, stream>>>(nei_idx, nei_mask, flagsArr, emb, Pbf, Cb);
  // Y = Cb @ Gt^T + bo2  [f32 out], K=2048; 32x64 tile -> 512 blocks (2/CU)
  k_mgemm<32, 64, 2, false><<<dim3(D / 64, BQ / 32), 256, 0, stream>>>(Cb, Gt, bo2, Y, BQ, D, 2048);
  k_ln<<<BQ, 256, 0, stream>>>(X, Y, ln1w, ln1b, S, Sb);
  // HH = relu(S@W1 + b1)  [bf16 out]; grid 512 blocks
  k_mgemm<128, 64, 3, true><<<dim3(DFF / 64, BQ / 128), 256, 0, stream>>>(Sb, W1t, b1, HHb, BQ, DFF, 256);
  // F = relu(HH@W2 + b2)  [f32 out]; 32x64 tile -> 512 blocks
  k_mgemm<32, 64, 3, false><<<dim3(D / 64, BQ / 32), 256, 0, stream>>>(HHb, W2t, b2, F, BQ, D, DFF);
  k_ln<<<BQ, 256, 0, stream>>>(S, F, ln2w, ln2b, out, nullptr);
}

// Round 8
// 119.641 us; speedup vs baseline: 1.8956x; 1.0223x over previous
//
#include <hip/hip_runtime.h>
#include <hip/hip_bf16.h>
#include <math.h>

// Problem constants
#define BQ   4096
#define D    256
#define NH   8
#define HD   32
#define LN_  64     // neighbors per node
#define DFF  1024
#define EPSV 1e-5f
#define QSCALE 0.17677669529663687f  // HD^-0.5

typedef __attribute__((ext_vector_type(8))) short short8;
typedef __attribute__((ext_vector_type(4))) float f32x4;

// LDS XOR swizzle (G4): spread 512B/128B-stride rows across banks; bijective involution.
#define ESWZ(row, byte) ((byte) ^ (((row) & 7) << 4))

// ---------------- helpers ----------------
__device__ __forceinline__ float wave_sum(float v){
#pragma unroll
  for (int off = 32; off; off >>= 1) v += __shfl_xor(v, off, 64);
  return v;
}
// native converts -> compiler emits v_cvt_pk_bf16_f32 (1 inst per pair)
__device__ __forceinline__ unsigned short f2bf(float f){
  __hip_bfloat16 h = __float2bfloat16(f);
  unsigned short r; __builtin_memcpy(&r, &h, 2); return r;
}
__device__ __forceinline__ unsigned pk2(float a, float b){
  __hip_bfloat162 h = __float22bfloat162_rn(make_float2(a, b));
  unsigned r; __builtin_memcpy(&r, &h, 4); return r;
}

// ---------------- mega-prep kernel (block-range dispatch) ----------------
__global__ __launch_bounds__(256) void k_prep(
    const float* __restrict__ Wq, const float* __restrict__ Wk,
    const float* __restrict__ Wv, const float* __restrict__ Wo,
    const float* __restrict__ W1, const float* __restrict__ W2,
    const float* __restrict__ bq, const float* __restrict__ bv,
    const float* __restrict__ bo,
    const int* __restrict__ batch, const float* __restrict__ emb,
    const unsigned int* __restrict__ maskw,
    unsigned short* __restrict__ W1t, unsigned short* __restrict__ W2t,
    unsigned short* __restrict__ Mt, unsigned short* __restrict__ Gt,
    float* __restrict__ pb, float* __restrict__ bo2,
    float* __restrict__ X, unsigned short* __restrict__ Xb,
    int* __restrict__ flagsArr){
  __shared__ float smem[4224];
  const int bid = blockIdx.x;
  const int tid = threadIdx.x;

  if (bid < 128){
    const float* src; unsigned short* dst; int K, N, t0;
    if (bid < 64){ src = W1; dst = W1t; K = 256;  N = 1024; t0 = bid; }
    else         { src = W2; dst = W2t; K = 1024; N = 256;  t0 = bid - 64; }
    const int ntx = N / 64;
    const int k0 = (t0 / ntx) * 64, n0 = (t0 % ntx) * 64;
    float (*Ts)[65] = (float(*)[65])smem;
    {
      int r = tid >> 2, c4 = (tid & 3) * 16;
#pragma unroll
      for (int i = 0; i < 4; i++)
        *(float4*)&Ts[r][c4 + i * 4] = *(const float4*)(src + (size_t)(k0 + r) * N + n0 + c4 + i * 4);
    }
    __syncthreads();
    {
      int n = tid >> 2, kc = (tid & 3) * 16;
      unsigned int pk[8];
#pragma unroll
      for (int i = 0; i < 8; i++)
        pk[i] = pk2(Ts[kc + 2 * i][n], Ts[kc + 2 * i + 1][n]);
      unsigned short* orow = dst + (size_t)(n0 + n) * K + k0 + kc;
      *(uint4*)(orow)     = *(uint4*)&pk[0];
      *(uint4*)(orow + 8) = *(uint4*)&pk[4];
    }
    return;
  }
  if (bid < 256){
    int t0 = bid - 128;
    int hd0 = (t0 & 31) * 64, c0 = (t0 >> 5) * 64;
    int h = hd0 >> 8, d0 = hd0 & 255;
    float (*WqS)[33] = (float(*)[33])smem;
    float (*WkS)[33] = (float(*)[33])(smem + 64 * 33);
#pragma unroll
    for (int s = 0; s < 2; s++){
      int idx = tid + s * 256;
      int row = idx >> 3, c4 = (idx & 7) * 4;
      *(float4*)&WqS[row][c4] = *(const float4*)(Wq + (size_t)(c0 + row) * 256 + h * 32 + c4);
      *(float4*)&WkS[row][c4] = *(const float4*)(Wk + (size_t)(d0 + row) * 256 + h * 32 + c4);
    }
    __syncthreads();
    int jo = (tid >> 4) * 4, io = (tid & 15) * 4;
    float acc[4][4];
#pragma unroll
    for (int j = 0; j < 4; j++)
#pragma unroll
      for (int i = 0; i < 4; i++) acc[j][i] = 0.f;
#pragma unroll
    for (int t = 0; t < 32; t++){
#pragma unroll
      for (int j = 0; j < 4; j++){
        float kv = WkS[jo + j][t];
#pragma unroll
        for (int i = 0; i < 4; i++) acc[j][i] = fmaf(kv, WqS[io + i][t], acc[j][i]);
      }
    }
#pragma unroll
    for (int j = 0; j < 4; j++){
      uint2 o;
      o.x = pk2(acc[j][0] * QSCALE, acc[j][1] * QSCALE);
      o.y = pk2(acc[j][2] * QSCALE, acc[j][3] * QSCALE);
      *(uint2*)(Mt + (size_t)(hd0 + jo + j) * 256 + c0 + io) = o;
    }
    if (c0 == 0 && tid < 64){
      float s = 0.f;
#pragma unroll
      for (int t = 0; t < 32; t++) s = fmaf(WkS[tid][t], bq[h * 32 + t], s);
      pb[hd0 + tid] = s * QSCALE;
    }
    return;
  }
  if (bid < 384){
    int t0 = bid - 256;
    int hd0 = (t0 & 31) * 64, n0 = (t0 >> 5) * 64;
    int h = hd0 >> 8, d0 = hd0 & 255;
    float (*WvS)[33] = (float(*)[33])smem;
    float (*WoS)[65] = (float(*)[65])(smem + 64 * 33);
#pragma unroll
    for (int s = 0; s < 2; s++){
      int idx = tid + s * 256;
      int row = idx >> 3, c4 = (idx & 7) * 4;
      *(float4*)&WvS[row][c4] = *(const float4*)(Wv + (size_t)(d0 + row) * 256 + h * 32 + c4);
      int row2 = idx >> 4, c42 = (idx & 15) * 4;
      *(float4*)&WoS[row2][c42] = *(const float4*)(Wo + (size_t)(h * 32 + row2) * 256 + n0 + c42);
    }
    __syncthreads();
    int jo = (tid >> 4) * 4, io = (tid & 15) * 4;
    float acc[4][4];
#pragma unroll
    for (int i = 0; i < 4; i++)
#pragma unroll
      for (int j = 0; j < 4; j++) acc[i][j] = 0.f;
#pragma unroll
    for (int t = 0; t < 32; t++){
#pragma unroll
      for (int i = 0; i < 4; i++){
        float ov = WoS[t][io + i];
#pragma unroll
        for (int j = 0; j < 4; j++) acc[i][j] = fmaf(ov, WvS[jo + j][t], acc[i][j]);
      }
    }
#pragma unroll
    for (int i = 0; i < 4; i++){
      uint2 o;
      o.x = pk2(acc[i][0], acc[i][1]);
      o.y = pk2(acc[i][2], acc[i][3]);
      *(uint2*)(Gt + (size_t)(n0 + io + i) * 2048 + hd0 + jo) = o;
    }
    return;
  }
  if (bid == 384){
    int n = tid;
    float s = bo[n];
    for (int j = 0; j < 256; j++) s = fmaf(bv[j], Wo[(size_t)j * 256 + n], s);
    bo2[n] = s;
    return;
  }
  if (bid < 641){
    int* df = (int*)smem;
    if (tid == 0) df[0] = 0;
    __syncthreads();
    int idx = (bid - 385) * 256 + tid;
    unsigned int v = maskw[idx];
    int bits = 0;
    if (v == 0x3F800000u) bits = 2;
    else if (v & 0xFFFFFF00u) bits = 1;
    int b2 = __any(bits & 2) ? 2 : 0;
    int b1 = __any(bits & 1) ? 1 : 0;
    if ((tid & 63) == 0 && (b1 | b2)) atomicOr(df, b1 | b2);
    __syncthreads();
    if (tid == 0) flagsArr[bid - 385] = df[0];
    return;
  }
  {
    int gid = (bid - 641) * 256 + tid;
    int b = gid >> 6, c = gid & 63;
    float4 v = ((const float4*)(emb + (size_t)batch[b] * D))[c];
    ((float4*)(X + (size_t)b * D))[c] = v;
    uint2 p;
    p.x = pk2(v.x, v.y);
    p.y = pk2(v.z, v.w);
    ((uint2*)Xb)[gid] = p;
  }
}

// ---------------- bf16 MFMA GEMM (direct staging) + XCD swizzle ----------------
template<int BM, int BN, int EPI, bool OUTBF>
__global__ __launch_bounds__(256) void k_mgemm(const unsigned short* __restrict__ A,
                                               const unsigned short* __restrict__ Bt,
                                               const float* __restrict__ bias,
                                               void* __restrict__ Cout,
                                               int M, int N, int K){
  constexpr int BK = 64;
  constexpr int WM = BM / 2, WN = BN / 2;
  constexpr int MR = WM / 16, NR = WN / 16;
  constexpr int AIT = BM * 8 / 256;
  constexpr int BIT = BN * 8 / 256;
  __shared__ __align__(16) unsigned short As[BM * BK];
  __shared__ __align__(16) unsigned short Bs[BN * BK];
  char* ab = (char*)As; char* bb = (char*)Bs;
  const int tid = threadIdx.x;
  const int w = tid >> 6, lane = tid & 63;
  const int wm = w >> 1, wn = w & 1;
  const int gx = gridDim.x;
  const int nwg = gx * gridDim.y;
  const int o = blockIdx.y * gx + blockIdx.x;
  const int lin = (o & 7) * (nwg >> 3) + (o >> 3);
  const int row0 = (lin / gx) * BM, col0 = (lin % gx) * BN;
  f32x4 acc[MR][NR];
#pragma unroll
  for (int m = 0; m < MR; m++)
#pragma unroll
    for (int n = 0; n < NR; n++) acc[m][n] = (f32x4){0.f, 0.f, 0.f, 0.f};

  for (int k0 = 0; k0 < K; k0 += BK){
#pragma unroll
    for (int s = 0; s < AIT; s++){
      int c = s * 256 + tid;
      int r = c >> 3, jj = c & 7;
      uint4 v = *(const uint4*)(A + (size_t)(row0 + r) * K + k0 + jj * 8);
      *(uint4*)(ab + ESWZ(r, r * 128 + jj * 16)) = v;
    }
#pragma unroll
    for (int s = 0; s < BIT; s++){
      int c = s * 256 + tid;
      int r = c >> 3, jj = c & 7;
      uint4 v = *(const uint4*)(Bt + (size_t)(col0 + r) * K + k0 + jj * 8);
      *(uint4*)(bb + ESWZ(r, r * 128 + jj * 16)) = v;
    }
    __syncthreads();
#pragma unroll
    for (int kk = 0; kk < 2; kk++){
      short8 af[MR], bf[NR];
#pragma unroll
      for (int m = 0; m < MR; m++){
        int r = wm * WM + m * 16 + (lane & 15);
        af[m] = *(const short8*)(ab + ESWZ(r, r * 128 + (kk * 4 + (lane >> 4)) * 16));
      }
#pragma unroll
      for (int n = 0; n < NR; n++){
        int r = wn * WN + n * 16 + (lane & 15);
        bf[n] = *(const short8*)(bb + ESWZ(r, r * 128 + (kk * 4 + (lane >> 4)) * 16));
      }
#pragma unroll
      for (int m = 0; m < MR; m++)
#pragma unroll
        for (int n = 0; n < NR; n++)
          acc[m][n] = __builtin_amdgcn_mfma_f32_16x16x32_bf16(af[m], bf[n], acc[m][n], 0, 0, 0);
    }
    __syncthreads();
  }
#pragma unroll
  for (int m = 0; m < MR; m++){
#pragma unroll
    for (int n = 0; n < NR; n++){
      int col = col0 + wn * WN + n * 16 + (lane & 15);
      float bsv = bias[col];
      int rbase = row0 + wm * WM + m * 16 + (lane >> 4) * 4;
#pragma unroll
      for (int r = 0; r < 4; r++){
        float v = acc[m][n][r] + bsv;
        if (EPI == 3) v = fmaxf(v, 0.f);
        if (OUTBF) ((unsigned short*)Cout)[(size_t)(rbase + r) * N + col] = f2bf(v);
        else       ((float*)Cout)[(size_t)(rbase + r) * N + col] = v;
      }
    }
  }
}

// ---------------- attention core: 256 threads, 4 waves; register-resident PV ----------------
__global__ __launch_bounds__(256) void k_attn(const int* __restrict__ nei_idx,
                                              const void* __restrict__ nei_mask,
                                              const int* __restrict__ flagsArr,
                                              const float* __restrict__ emb,
                                              const unsigned short* __restrict__ Pb,
                                              unsigned short* __restrict__ Cb){
  const int b = blockIdx.x;
  const int tid = threadIdx.x;
  const int w = tid >> 6, lane = tid & 63;
  __shared__ __align__(16) unsigned short Ebf[64 * 256];  // 32 KB, swizzled; reused as PV partials
  __shared__ __align__(16) unsigned short Pl[9 * 256];    // 4.5 KB, row 8 = zeros
  __shared__ float sc[NH * LN_];                          // 2 KB
  __shared__ float mskv[LN_];
  __shared__ int   fred[4];
  char* eb = (char*)Ebf;
  char* pl = (char*)Pl;
  float* pf = (float*)Ebf;   // PV partials: [wave][h][d] = 4*8*256 f32 = 32 KB

  // flags OR-reduce
  {
    int f = flagsArr[tid];
#pragma unroll
    for (int off = 32; off; off >>= 1) f |= __shfl_xor(f, off, 64);
    if (lane == 0) fred[w] = f;
  }
  // issue all 16 E-row loads up front; vr stays live through PV (f32 precision)
  float4 vr[16];
#pragma unroll
  for (int i = 0; i < 16; i++){
    int nid = nei_idx[(size_t)b * LN_ + w * 16 + i];
    vr[i] = ((const float4*)(emb + (size_t)nid * D))[lane];
  }
  // stage P[b] (bf16) into swizzled LDS; zero pad row 8
  {
    int r = tid >> 5, cb16 = (tid & 31) * 16;
    uint4 v = *(const uint4*)((const char*)Pb + (size_t)b * 4096 + r * 512 + cb16);
    *(uint4*)(pl + ESWZ(r, r * 512 + cb16)) = v;
  }
  if (tid < 64) *(uint2*)(pl + 8 * 512 + tid * 8) = make_uint2(0u, 0u);
  __syncthreads();   // fred ready

  // pack + write E rows (bf16) to swizzled LDS for the scores MFMA
#pragma unroll
  for (int i = 0; i < 16; i++){
    int l = w * 16 + i;
    uint2 p;
    p.x = pk2(vr[i].x, vr[i].y);
    p.y = pk2(vr[i].z, vr[i].w);
    *(uint2*)(eb + ESWZ(l, l * 512 + lane * 8)) = p;
  }
  // mask load (needs fred)
  if (tid < LN_){
    int fl = fred[0] | fred[1] | fred[2] | fred[3];
    int mf = (fl & 2) ? 2 : ((fl & 1) ? 1 : 0);
    bool m;
    if (mf == 1)      m = ((const unsigned char*)nei_mask)[(size_t)b * LN_ + tid] != 0;
    else if (mf == 2) m = ((const float*)nei_mask)[(size_t)b * LN_ + tid] != 0.f;
    else              m = ((const int*)nei_mask)[(size_t)b * LN_ + tid] != 0;
    mskv[tid] = m ? 1.f : 0.f;
  }
  __syncthreads();

  // scores^T[h, l] via MFMA chain: A = P rows (8 real + zero pad), B = E rows (own wave's tile)
  {
    const int hr = lane & 15;
    const int arow = hr < 8 ? hr : 8;
    const int bl = w * 16 + (lane & 15);
    const int koff = (lane >> 4) * 16;
    f32x4 acc = {0.f, 0.f, 0.f, 0.f};
    __builtin_amdgcn_s_setprio(1);
#pragma unroll
    for (int kk = 0; kk < 8; kk++){
      short8 af = *(const short8*)(pl + ESWZ(arow, arow * 512 + kk * 64 + koff));
      short8 bf = *(const short8*)(eb + ESWZ(bl, bl * 512 + kk * 64 + koff));
      acc = __builtin_amdgcn_mfma_f32_16x16x32_bf16(af, bf, acc, 0, 0, 0);
    }
    __builtin_amdgcn_s_setprio(0);
    int hb = (lane >> 4) * 4;
    if (hb < 8){
#pragma unroll
      for (int r = 0; r < 4; r++) sc[(hb + r) * LN_ + bl] = acc[r];
    }
  }
  __syncthreads();

  // softmax: 8 h-groups x 32 threads, each thread covers l = j and j+32
  {
    int h = tid >> 5, j = tid & 31;
    float v0 = mskv[j]      > 0.5f ? -INFINITY : sc[h * LN_ + j];
    float v1 = mskv[j + 32] > 0.5f ? -INFINITY : sc[h * LN_ + j + 32];
    float m = fmaxf(v0, v1);
#pragma unroll
    for (int off = 16; off; off >>= 1) m = fmaxf(m, __shfl_xor(m, off, 64));
    float e0 = __expf(v0 - m), e1 = __expf(v1 - m);
    float s = e0 + e1;
#pragma unroll
    for (int off = 16; off; off >>= 1) s += __shfl_xor(s, off, 64);
    float inv = 1.f / s;
    sc[h * LN_ + j]      = e0 * inv;
    sc[h * LN_ + j + 32] = e1 * inv;
  }
  __syncthreads();   // after this, Ebf (bf16 tile) is dead -> reuse as pf partials

  // PV from registers: wave w covers its 16 rows for ALL 8 heads (f32 E, no unpack)
  {
    float4 acc[NH];
#pragma unroll
    for (int h = 0; h < NH; h++) acc[h] = make_float4(0.f, 0.f, 0.f, 0.f);
#pragma unroll
    for (int i = 0; i < 16; i++){
      int l = w * 16 + i;
#pragma unroll
      for (int h = 0; h < NH; h++){
        float t = sc[h * LN_ + l];
        acc[h].x = fmaf(t, vr[i].x, acc[h].x);
        acc[h].y = fmaf(t, vr[i].y, acc[h].y);
        acc[h].z = fmaf(t, vr[i].z, acc[h].z);
        acc[h].w = fmaf(t, vr[i].w, acc[h].w);
      }
    }
#pragma unroll
    for (int h = 0; h < NH; h++)
      *(float4*)&pf[w * 2048 + h * 256 + lane * 4] = acc[h];
  }
  __syncthreads();

  // combine partials + bf16 pack + write C
#pragma unroll
  for (int s = 0; s < 2; s++){
    int gi = tid + s * 256;            // 512 float4-groups: h = gi>>6, d4 = gi&63
    int h = gi >> 6, d4 = gi & 63;
    float4 v0 = *(float4*)&pf[0 * 2048 + h * 256 + d4 * 4];
    float4 v1 = *(float4*)&pf[1 * 2048 + h * 256 + d4 * 4];
    float4 v2 = *(float4*)&pf[2 * 2048 + h * 256 + d4 * 4];
    float4 v3 = *(float4*)&pf[3 * 2048 + h * 256 + d4 * 4];
    float x = v0.x + v1.x + v2.x + v3.x;
    float y = v0.y + v1.y + v2.y + v3.y;
    float z = v0.z + v1.z + v2.z + v3.z;
    float u = v0.w + v1.w + v2.w + v3.w;
    uint2 o;
    o.x = pk2(x, y);
    o.y = pk2(z, u);
    *(uint2*)(Cb + (size_t)b * 2048 + h * 256 + d4 * 4) = o;
  }
}

// ---------------- LayerNorm(out = LN(A+B)), optional bf16 copy ----------------
__global__ __launch_bounds__(256) void k_ln(const float* __restrict__ A,
                                            const float* __restrict__ Bv,
                                            const float* __restrict__ w,
                                            const float* __restrict__ bi,
                                            float* __restrict__ out,
                                            unsigned short* __restrict__ outb){
  const int row = blockIdx.x, tid = threadIdx.x;
  const int wv = tid >> 6, lane = tid & 63;
  __shared__ float red[8];
  float v = A[(size_t)row * D + tid] + Bv[(size_t)row * D + tid];
  float s = wave_sum(v);
  if (lane == 0) red[wv] = s;
  __syncthreads();
  float mu = (red[0] + red[1] + red[2] + red[3]) * (1.f / D);
  float d = v - mu;
  float s2 = wave_sum(d * d);
  if (lane == 0) red[4 + wv] = s2;
  __syncthreads();
  float var = (red[4] + red[5] + red[6] + red[7]) * (1.f / D);
  float res = d * rsqrtf(var + EPSV) * w[tid] + bi[tid];
  out[(size_t)row * D + tid] = res;
  if (outb) outb[(size_t)row * D + tid] = f2bf(res);
}

// ---------------- launch ----------------
extern "C" void kernel_launch(void* const* d_in, const int* in_sizes, int n_in,
                              void* d_out, int out_size, void* d_ws, size_t ws_size,
                              hipStream_t stream){
  (void)in_sizes; (void)n_in; (void)out_size; (void)ws_size;
  const int*   batch    = (const int*)d_in[0];
  const int*   nei_idx  = (const int*)d_in[1];
  const void*  nei_mask = d_in[2];
  const float* emb      = (const float*)d_in[3];
  const float* Wq = (const float*)d_in[4];  const float* bq = (const float*)d_in[5];
  const float* Wk = (const float*)d_in[6];  /* bk dropped: softmax-invariant */
  const float* Wv = (const float*)d_in[8];  const float* bv = (const float*)d_in[9];
  const float* Wo = (const float*)d_in[10]; const float* bo = (const float*)d_in[11];
  const float* W1 = (const float*)d_in[12]; const float* b1 = (const float*)d_in[13];
  const float* W2 = (const float*)d_in[14]; const float* b2 = (const float*)d_in[15];
  const float* ln1w = (const float*)d_in[16]; const float* ln1b = (const float*)d_in[17];
  const float* ln2w = (const float*)d_in[18]; const float* ln2b = (const float*)d_in[19];

  float* ws = (float*)d_ws;
  // 4-MiB slots
  float* X  = ws;                        // slot 0
  float* Y  = ws + (size_t)1 * 1048576;  // slot 1
  float* S  = ws + (size_t)2 * 1048576;  // slot 2
  float* F  = ws + (size_t)3 * 1048576;  // slot 3
  unsigned short* Pbf = (unsigned short*)(ws + (size_t)4 * 1048576);  // slots 4-7 [4096][2048]
  unsigned short* Cb  = Pbf;             // alias: attn block b reads P[b] fully before writing C[b]
  unsigned short* Sb  = (unsigned short*)(ws + (size_t)8 * 1048576);  // slot 8
  unsigned short* HHb = (unsigned short*)(ws + (size_t)9 * 1048576);  // slots 9-10
  unsigned short* Xb  = (unsigned short*)(ws + (size_t)11 * 1048576); // slot 11
  char* wb = (char*)(ws + (size_t)12 * 1048576);
  unsigned short* W1t = (unsigned short*)(wb);                        // 512 KiB
  unsigned short* W2t = (unsigned short*)(wb + (512u << 10));         // 512 KiB
  unsigned short* Mt  = (unsigned short*)(wb + (1024u << 10));        // 1 MiB
  unsigned short* Gt  = (unsigned short*)(wb + (2048u << 10));        // 1 MiB
  float* pbv  = (float*)(wb + (3072u << 10));                         // 8 KiB
  float* bo2  = (float*)(wb + (3072u << 10) + 8192);                  // 1 KiB
  int*   flagsArr = (int*)(wb + (3072u << 10) + 16384);               // 256 ints
  float* out = (float*)d_out;

  k_prep<<<1665, 256, 0, stream>>>(Wq, Wk, Wv, Wo, W1, W2, bq, bv, bo,
                                   batch, emb, (const unsigned int*)nei_mask,
                                   W1t, W2t, Mt, Gt, pbv, bo2, X, Xb, flagsArr);
  // P = Xb @ Mt^T + pb  [bf16 out], N=2048
  k_mgemm<128, 64, 2, true><<<dim3(2048 / 64, BQ / 128), 256, 0, stream>>>(Xb, Mt, pbv, Pbf, BQ, 2048, 256);
  k_attn<<<BQ, 256, 0, stream>>>(nei_idx, nei_mask, flagsArr, emb, Pbf, Cb);
  // Y = Cb @ Gt^T + bo2  [f32 out], K=2048
  k_mgemm<32, 64, 2, false><<<dim3(D / 64, BQ / 32), 256, 0, stream>>>(Cb, Gt, bo2, Y, BQ, D, 2048);
  k_ln<<<BQ, 256, 0, stream>>>(X, Y, ln1w, ln1b, S, Sb);
  // HH = relu(S@W1 + b1)  [bf16 out]
  k_mgemm<128, 64, 3, true><<<dim3(DFF / 64, BQ / 128), 256, 0, stream>>>(Sb, W1t, b1, HHb, BQ, DFF, 256);
  // F = relu(HH@W2 + b2)  [f32 out]
  k_mgemm<32, 64, 3, false><<<dim3(D / 64, BQ / 32), 256, 0, stream>>>(HHb, W2t, b2, F, BQ, D, DFF);
  k_ln<<<BQ, 256, 0, stream>>>(S, F, ln2w, ln2b, out, nullptr);
}

// Round 9
// 119.577 us; speedup vs baseline: 1.8966x; 1.0005x over previous
//
#include <hip/hip_runtime.h>
#include <hip/hip_bf16.h>
#include <math.h>

// Problem constants
#define BQ   4096
#define D    256
#define NH   8
#define HD   32
#define LN_  64     // neighbors per node
#define DFF  1024
#define EPSV 1e-5f
#define QSCALE 0.17677669529663687f  // HD^-0.5

typedef __attribute__((ext_vector_type(8))) short short8;
typedef __attribute__((ext_vector_type(4))) float f32x4;

// LDS XOR swizzle (G4): spread 512B/256B/128B-stride rows across banks; bijective involution.
#define ESWZ(row, byte) ((byte) ^ (((row) & 7) << 4))

// ---------------- helpers ----------------
__device__ __forceinline__ float wave_sum(float v){
#pragma unroll
  for (int off = 32; off; off >>= 1) v += __shfl_xor(v, off, 64);
  return v;
}
// native converts -> compiler emits v_cvt_pk_bf16_f32 (1 inst per pair)
__device__ __forceinline__ unsigned short f2bf(float f){
  __hip_bfloat16 h = __float2bfloat16(f);
  unsigned short r; __builtin_memcpy(&r, &h, 2); return r;
}
__device__ __forceinline__ unsigned pk2(float a, float b){
  __hip_bfloat162 h = __float22bfloat162_rn(make_float2(a, b));
  unsigned r; __builtin_memcpy(&r, &h, 4); return r;
}
__device__ __forceinline__ float bflo(unsigned u){ return __uint_as_float(u << 16); }
__device__ __forceinline__ float bfhi(unsigned u){ return __uint_as_float(u & 0xFFFF0000u); }

// ---------------- mega-prep kernel (block-range dispatch) ----------------
__global__ __launch_bounds__(256) void k_prep(
    const float* __restrict__ Wq, const float* __restrict__ Wk,
    const float* __restrict__ Wv, const float* __restrict__ Wo,
    const float* __restrict__ W1, const float* __restrict__ W2,
    const float* __restrict__ bq, const float* __restrict__ bv,
    const float* __restrict__ bo,
    const int* __restrict__ batch, const float* __restrict__ emb,
    const unsigned int* __restrict__ maskw,
    unsigned short* __restrict__ W1t, unsigned short* __restrict__ W2t,
    unsigned short* __restrict__ Mt, unsigned short* __restrict__ Gt,
    float* __restrict__ pb, float* __restrict__ bo2,
    float* __restrict__ X, unsigned short* __restrict__ Xb,
    int* __restrict__ flagsArr){
  __shared__ float smem[4224];
  const int bid = blockIdx.x;
  const int tid = threadIdx.x;

  if (bid < 128){
    const float* src; unsigned short* dst; int K, N, t0;
    if (bid < 64){ src = W1; dst = W1t; K = 256;  N = 1024; t0 = bid; }
    else         { src = W2; dst = W2t; K = 1024; N = 256;  t0 = bid - 64; }
    const int ntx = N / 64;
    const int k0 = (t0 / ntx) * 64, n0 = (t0 % ntx) * 64;
    float (*Ts)[65] = (float(*)[65])smem;
    {
      int r = tid >> 2, c4 = (tid & 3) * 16;
#pragma unroll
      for (int i = 0; i < 4; i++)
        *(float4*)&Ts[r][c4 + i * 4] = *(const float4*)(src + (size_t)(k0 + r) * N + n0 + c4 + i * 4);
    }
    __syncthreads();
    {
      int n = tid >> 2, kc = (tid & 3) * 16;
      unsigned int pk[8];
#pragma unroll
      for (int i = 0; i < 8; i++)
        pk[i] = pk2(Ts[kc + 2 * i][n], Ts[kc + 2 * i + 1][n]);
      unsigned short* orow = dst + (size_t)(n0 + n) * K + k0 + kc;
      *(uint4*)(orow)     = *(uint4*)&pk[0];
      *(uint4*)(orow + 8) = *(uint4*)&pk[4];
    }
    return;
  }
  if (bid < 256){
    int t0 = bid - 128;
    int hd0 = (t0 & 31) * 64, c0 = (t0 >> 5) * 64;
    int h = hd0 >> 8, d0 = hd0 & 255;
    float (*WqS)[33] = (float(*)[33])smem;
    float (*WkS)[33] = (float(*)[33])(smem + 64 * 33);
#pragma unroll
    for (int s = 0; s < 2; s++){
      int idx = tid + s * 256;
      int row = idx >> 3, c4 = (idx & 7) * 4;
      *(float4*)&WqS[row][c4] = *(const float4*)(Wq + (size_t)(c0 + row) * 256 + h * 32 + c4);
      *(float4*)&WkS[row][c4] = *(const float4*)(Wk + (size_t)(d0 + row) * 256 + h * 32 + c4);
    }
    __syncthreads();
    int jo = (tid >> 4) * 4, io = (tid & 15) * 4;
    float acc[4][4];
#pragma unroll
    for (int j = 0; j < 4; j++)
#pragma unroll
      for (int i = 0; i < 4; i++) acc[j][i] = 0.f;
#pragma unroll
    for (int t = 0; t < 32; t++){
#pragma unroll
      for (int j = 0; j < 4; j++){
        float kv = WkS[jo + j][t];
#pragma unroll
        for (int i = 0; i < 4; i++) acc[j][i] = fmaf(kv, WqS[io + i][t], acc[j][i]);
      }
    }
#pragma unroll
    for (int j = 0; j < 4; j++){
      uint2 o;
      o.x = pk2(acc[j][0] * QSCALE, acc[j][1] * QSCALE);
      o.y = pk2(acc[j][2] * QSCALE, acc[j][3] * QSCALE);
      *(uint2*)(Mt + (size_t)(hd0 + jo + j) * 256 + c0 + io) = o;
    }
    if (c0 == 0 && tid < 64){
      float s = 0.f;
#pragma unroll
      for (int t = 0; t < 32; t++) s = fmaf(WkS[tid][t], bq[h * 32 + t], s);
      pb[hd0 + tid] = s * QSCALE;
    }
    return;
  }
  if (bid < 384){
    int t0 = bid - 256;
    int hd0 = (t0 & 31) * 64, n0 = (t0 >> 5) * 64;
    int h = hd0 >> 8, d0 = hd0 & 255;
    float (*WvS)[33] = (float(*)[33])smem;
    float (*WoS)[65] = (float(*)[65])(smem + 64 * 33);
#pragma unroll
    for (int s = 0; s < 2; s++){
      int idx = tid + s * 256;
      int row = idx >> 3, c4 = (idx & 7) * 4;
      *(float4*)&WvS[row][c4] = *(const float4*)(Wv + (size_t)(d0 + row) * 256 + h * 32 + c4);
      int row2 = idx >> 4, c42 = (idx & 15) * 4;
      *(float4*)&WoS[row2][c42] = *(const float4*)(Wo + (size_t)(h * 32 + row2) * 256 + n0 + c42);
    }
    __syncthreads();
    int jo = (tid >> 4) * 4, io = (tid & 15) * 4;
    float acc[4][4];
#pragma unroll
    for (int i = 0; i < 4; i++)
#pragma unroll
      for (int j = 0; j < 4; j++) acc[i][j] = 0.f;
#pragma unroll
    for (int t = 0; t < 32; t++){
#pragma unroll
      for (int i = 0; i < 4; i++){
        float ov = WoS[t][io + i];
#pragma unroll
        for (int j = 0; j < 4; j++) acc[i][j] = fmaf(ov, WvS[jo + j][t], acc[i][j]);
      }
    }
#pragma unroll
    for (int i = 0; i < 4; i++){
      uint2 o;
      o.x = pk2(acc[i][0], acc[i][1]);
      o.y = pk2(acc[i][2], acc[i][3]);
      *(uint2*)(Gt + (size_t)(n0 + io + i) * 2048 + hd0 + jo) = o;
    }
    return;
  }
  if (bid == 384){
    int n = tid;
    float s = bo[n];
    for (int j = 0; j < 256; j++) s = fmaf(bv[j], Wo[(size_t)j * 256 + n], s);
    bo2[n] = s;
    return;
  }
  if (bid < 641){
    int* df = (int*)smem;
    if (tid == 0) df[0] = 0;
    __syncthreads();
    int idx = (bid - 385) * 256 + tid;
    unsigned int v = maskw[idx];
    int bits = 0;
    if (v == 0x3F800000u) bits = 2;
    else if (v & 0xFFFFFF00u) bits = 1;
    int b2 = __any(bits & 2) ? 2 : 0;
    int b1 = __any(bits & 1) ? 1 : 0;
    if ((tid & 63) == 0 && (b1 | b2)) atomicOr(df, b1 | b2);
    __syncthreads();
    if (tid == 0) flagsArr[bid - 385] = df[0];
    return;
  }
  {
    int gid = (bid - 641) * 256 + tid;
    int b = gid >> 6, c = gid & 63;
    float4 v = ((const float4*)(emb + (size_t)batch[b] * D))[c];
    ((float4*)(X + (size_t)b * D))[c] = v;
    uint2 p;
    p.x = pk2(v.x, v.y);
    p.y = pk2(v.z, v.w);
    ((uint2*)Xb)[gid] = p;
  }
}

// ---------------- bf16 MFMA GEMM (direct staging) + XCD swizzle ----------------
template<int BM, int BN, int EPI, bool OUTBF>
__global__ __launch_bounds__(256) void k_mgemm(const unsigned short* __restrict__ A,
                                               const unsigned short* __restrict__ Bt,
                                               const float* __restrict__ bias,
                                               void* __restrict__ Cout,
                                               int M, int N, int K){
  constexpr int BK = 64;
  constexpr int WM = BM / 2, WN = BN / 2;
  constexpr int MR = WM / 16, NR = WN / 16;
  constexpr int AIT = BM * 8 / 256;
  constexpr int BIT = BN * 8 / 256;
  __shared__ __align__(16) unsigned short As[BM * BK];
  __shared__ __align__(16) unsigned short Bs[BN * BK];
  char* ab = (char*)As; char* bb = (char*)Bs;
  const int tid = threadIdx.x;
  const int w = tid >> 6, lane = tid & 63;
  const int wm = w >> 1, wn = w & 1;
  const int gx = gridDim.x;
  const int nwg = gx * gridDim.y;
  const int o = blockIdx.y * gx + blockIdx.x;
  const int lin = (o & 7) * (nwg >> 3) + (o >> 3);
  const int row0 = (lin / gx) * BM, col0 = (lin % gx) * BN;
  f32x4 acc[MR][NR];
#pragma unroll
  for (int m = 0; m < MR; m++)
#pragma unroll
    for (int n = 0; n < NR; n++) acc[m][n] = (f32x4){0.f, 0.f, 0.f, 0.f};

  for (int k0 = 0; k0 < K; k0 += BK){
#pragma unroll
    for (int s = 0; s < AIT; s++){
      int c = s * 256 + tid;
      int r = c >> 3, jj = c & 7;
      uint4 v = *(const uint4*)(A + (size_t)(row0 + r) * K + k0 + jj * 8);
      *(uint4*)(ab + ESWZ(r, r * 128 + jj * 16)) = v;
    }
#pragma unroll
    for (int s = 0; s < BIT; s++){
      int c = s * 256 + tid;
      int r = c >> 3, jj = c & 7;
      uint4 v = *(const uint4*)(Bt + (size_t)(col0 + r) * K + k0 + jj * 8);
      *(uint4*)(bb + ESWZ(r, r * 128 + jj * 16)) = v;
    }
    __syncthreads();
#pragma unroll
    for (int kk = 0; kk < 2; kk++){
      short8 af[MR], bf[NR];
#pragma unroll
      for (int m = 0; m < MR; m++){
        int r = wm * WM + m * 16 + (lane & 15);
        af[m] = *(const short8*)(ab + ESWZ(r, r * 128 + (kk * 4 + (lane >> 4)) * 16));
      }
#pragma unroll
      for (int n = 0; n < NR; n++){
        int r = wn * WN + n * 16 + (lane & 15);
        bf[n] = *(const short8*)(bb + ESWZ(r, r * 128 + (kk * 4 + (lane >> 4)) * 16));
      }
#pragma unroll
      for (int m = 0; m < MR; m++)
#pragma unroll
        for (int n = 0; n < NR; n++)
          acc[m][n] = __builtin_amdgcn_mfma_f32_16x16x32_bf16(af[m], bf[n], acc[m][n], 0, 0, 0);
    }
    __syncthreads();
  }
#pragma unroll
  for (int m = 0; m < MR; m++){
#pragma unroll
    for (int n = 0; n < NR; n++){
      int col = col0 + wn * WN + n * 16 + (lane & 15);
      float bsv = bias[col];
      int rbase = row0 + wm * WM + m * 16 + (lane >> 4) * 4;
#pragma unroll
      for (int r = 0; r < 4; r++){
        float v = acc[m][n][r] + bsv;
        if (EPI == 3) v = fmaxf(v, 0.f);
        if (OUTBF) ((unsigned short*)Cout)[(size_t)(rbase + r) * N + col] = f2bf(v);
        else       ((float*)Cout)[(size_t)(rbase + r) * N + col] = v;
      }
    }
  }
}

// ---------------- attention core: 23.3 KB LDS (6 blocks/CU), split-K scores ----------------
// E tile staged as two [64][128] bf16 k-halves in 16 KB; PV from f32 regs; partials bf16
// reuse the same 16 KB. Target: occupancy 29% -> ~60-75% (residency was the r8 limiter).
__global__ __launch_bounds__(256) void k_attn(const int* __restrict__ nei_idx,
                                              const void* __restrict__ nei_mask,
                                              const int* __restrict__ flagsArr,
                                              const float* __restrict__ emb,
                                              const unsigned short* __restrict__ Pb,
                                              unsigned short* __restrict__ Cb){
  const int b = blockIdx.x;
  const int tid = threadIdx.x;
  const int w = tid >> 6, lane = tid & 63;
  __shared__ __align__(16) unsigned short EbfH[64 * 128]; // 16 KB: E k-half tile / PV partials
  __shared__ __align__(16) unsigned short Pl[9 * 256];    // 4.5 KB, row 8 = zeros
  __shared__ float sc[NH * LN_];                          // 2 KB
  __shared__ float mskv[LN_];
  __shared__ int   fred[4];
  char* eb = (char*)EbfH;
  char* pl = (char*)Pl;
  unsigned* pfu = (unsigned*)EbfH;   // partials: [wave][h][d/2] = 4*8*128 u32 = 16 KB

  // flags OR-reduce
  {
    int f = flagsArr[tid];
#pragma unroll
    for (int off = 32; off; off >>= 1) f |= __shfl_xor(f, off, 64);
    if (lane == 0) fred[w] = f;
  }
  // issue all 16 E-row loads up front; vr stays live through PV (f32 precision)
  float4 vr[16];
#pragma unroll
  for (int i = 0; i < 16; i++){
    int nid = nei_idx[(size_t)b * LN_ + w * 16 + i];
    vr[i] = ((const float4*)(emb + (size_t)nid * D))[lane];
  }
  // stage P[b] (bf16) into swizzled LDS; zero pad row 8
  {
    int r = tid >> 5, cb16 = (tid & 31) * 16;
    uint4 v = *(const uint4*)((const char*)Pb + (size_t)b * 4096 + r * 512 + cb16);
    *(uint4*)(pl + ESWZ(r, r * 512 + cb16)) = v;
  }
  if (tid < 64) *(uint2*)(pl + 8 * 512 + tid * 8) = make_uint2(0u, 0u);
  __syncthreads();   // fred + Pl ready

  // mask load (needs fred)
  if (tid < LN_){
    int fl = fred[0] | fred[1] | fred[2] | fred[3];
    int mf = (fl & 2) ? 2 : ((fl & 1) ? 1 : 0);
    bool m;
    if (mf == 1)      m = ((const unsigned char*)nei_mask)[(size_t)b * LN_ + tid] != 0;
    else if (mf == 2) m = ((const float*)nei_mask)[(size_t)b * LN_ + tid] != 0.f;
    else              m = ((const int*)nei_mask)[(size_t)b * LN_ + tid] != 0;
    mskv[tid] = m ? 1.f : 0.f;
  }

  // ---- scores, split-K: acc carried across two half-tile passes ----
  f32x4 acc = {0.f, 0.f, 0.f, 0.f};
  const int hr = lane & 15;
  const int arow = hr < 8 ? hr : 8;
  const int bl = w * 16 + (lane & 15);
  const int koff = (lane >> 4) * 16;
#pragma unroll
  for (int half = 0; half < 2; half++){
    // stage k-half: lanes owning this half (lane>>5 == half) write their 16 rows
    if ((lane >> 5) == half){
      int cl = lane & 31;                       // col-quad within half
#pragma unroll
      for (int i = 0; i < 16; i++){
        int l = w * 16 + i;
        uint2 p;
        p.x = pk2(vr[i].x, vr[i].y);
        p.y = pk2(vr[i].z, vr[i].w);
        *(uint2*)(eb + ESWZ(l, l * 256 + cl * 8)) = p;
      }
    }
    __syncthreads();
    __builtin_amdgcn_s_setprio(1);
#pragma unroll
    for (int kk = 0; kk < 4; kk++){
      int kabs = half * 4 + kk;
      short8 af = *(const short8*)(pl + ESWZ(arow, arow * 512 + kabs * 64 + koff));
      short8 bf = *(const short8*)(eb + ESWZ(bl, bl * 256 + kk * 64 + koff));
      acc = __builtin_amdgcn_mfma_f32_16x16x32_bf16(af, bf, acc, 0, 0, 0);
    }
    __builtin_amdgcn_s_setprio(0);
    __syncthreads();
  }
  {
    int hb = (lane >> 4) * 4;
    if (hb < 8){
#pragma unroll
      for (int r = 0; r < 4; r++) sc[(hb + r) * LN_ + bl] = acc[r];
    }
  }
  __syncthreads();

  // softmax: 8 h-groups x 32 threads, each thread covers l = j and j+32
  {
    int h = tid >> 5, j = tid & 31;
    float v0 = mskv[j]      > 0.5f ? -INFINITY : sc[h * LN_ + j];
    float v1 = mskv[j + 32] > 0.5f ? -INFINITY : sc[h * LN_ + j + 32];
    float m = fmaxf(v0, v1);
#pragma unroll
    for (int off = 16; off; off >>= 1) m = fmaxf(m, __shfl_xor(m, off, 64));
    float e0 = __expf(v0 - m), e1 = __expf(v1 - m);
    float s = e0 + e1;
#pragma unroll
    for (int off = 16; off; off >>= 1) s += __shfl_xor(s, off, 64);
    float inv = 1.f / s;
    sc[h * LN_ + j]      = e0 * inv;
    sc[h * LN_ + j + 32] = e1 * inv;
  }
  __syncthreads();   // E half-tile dead -> reuse as bf16 partials

  // PV from registers: wave w covers its 16 rows for ALL 8 heads (f32 E, no unpack)
  {
    float4 pacc[NH];
#pragma unroll
    for (int h = 0; h < NH; h++) pacc[h] = make_float4(0.f, 0.f, 0.f, 0.f);
#pragma unroll
    for (int i = 0; i < 16; i++){
      int l = w * 16 + i;
#pragma unroll
      for (int h = 0; h < NH; h++){
        float t = sc[h * LN_ + l];
        pacc[h].x = fmaf(t, vr[i].x, pacc[h].x);
        pacc[h].y = fmaf(t, vr[i].y, pacc[h].y);
        pacc[h].z = fmaf(t, vr[i].z, pacc[h].z);
        pacc[h].w = fmaf(t, vr[i].w, pacc[h].w);
      }
    }
    // pack partials to bf16: [w][h][lane*2 .. +1] u32-pairs
#pragma unroll
    for (int h = 0; h < NH; h++){
      uint2 p;
      p.x = pk2(pacc[h].x, pacc[h].y);
      p.y = pk2(pacc[h].z, pacc[h].w);
      *(uint2*)&pfu[w * 1024 + h * 128 + lane * 2] = p;
    }
  }
  __syncthreads();

  // combine bf16 partials + write C
#pragma unroll
  for (int s = 0; s < 2; s++){
    int gi = tid + s * 256;            // 512 uint2-groups: h = gi>>6, d4 = gi&63
    int h = gi >> 6, d4 = gi & 63;
    float x = 0.f, y = 0.f, z = 0.f, u = 0.f;
#pragma unroll
    for (int wv = 0; wv < 4; wv++){
      uint2 p = *(uint2*)&pfu[wv * 1024 + h * 128 + d4 * 2];
      x += bflo(p.x); y += bfhi(p.x);
      z += bflo(p.y); u += bfhi(p.y);
    }
    uint2 o;
    o.x = pk2(x, y);
    o.y = pk2(z, u);
    *(uint2*)(Cb + (size_t)b * 2048 + h * 256 + d4 * 4) = o;
  }
}

// ---------------- LayerNorm(out = LN(A+B)), optional bf16 copy ----------------
__global__ __launch_bounds__(256) void k_ln(const float* __restrict__ A,
                                            const float* __restrict__ Bv,
                                            const float* __restrict__ w,
                                            const float* __restrict__ bi,
                                            float* __restrict__ out,
                                            unsigned short* __restrict__ outb){
  const int row = blockIdx.x, tid = threadIdx.x;
  const int wv = tid >> 6, lane = tid & 63;
  __shared__ float red[8];
  float v = A[(size_t)row * D + tid] + Bv[(size_t)row * D + tid];
  float s = wave_sum(v);
  if (lane == 0) red[wv] = s;
  __syncthreads();
  float mu = (red[0] + red[1] + red[2] + red[3]) * (1.f / D);
  float d = v - mu;
  float s2 = wave_sum(d * d);
  if (lane == 0) red[4 + wv] = s2;
  __syncthreads();
  float var = (red[4] + red[5] + red[6] + red[7]) * (1.f / D);
  float res = d * rsqrtf(var + EPSV) * w[tid] + bi[tid];
  out[(size_t)row * D + tid] = res;
  if (outb) outb[(size_t)row * D + tid] = f2bf(res);
}

// ---------------- launch ----------------
extern "C" void kernel_launch(void* const* d_in, const int* in_sizes, int n_in,
                              void* d_out, int out_size, void* d_ws, size_t ws_size,
                              hipStream_t stream){
  (void)in_sizes; (void)n_in; (void)out_size; (void)ws_size;
  const int*   batch    = (const int*)d_in[0];
  const int*   nei_idx  = (const int*)d_in[1];
  const void*  nei_mask = d_in[2];
  const float* emb      = (const float*)d_in[3];
  const float* Wq = (const float*)d_in[4];  const float* bq = (const float*)d_in[5];
  const float* Wk = (const float*)d_in[6];  /* bk dropped: softmax-invariant */
  const float* Wv = (const float*)d_in[8];  const float* bv = (const float*)d_in[9];
  const float* Wo = (const float*)d_in[10]; const float* bo = (const float*)d_in[11];
  const float* W1 = (const float*)d_in[12]; const float* b1 = (const float*)d_in[13];
  const float* W2 = (const float*)d_in[14]; const float* b2 = (const float*)d_in[15];
  const float* ln1w = (const float*)d_in[16]; const float* ln1b = (const float*)d_in[17];
  const float* ln2w = (const float*)d_in[18]; const float* ln2b = (const float*)d_in[19];

  float* ws = (float*)d_ws;
  // 4-MiB slots
  float* X  = ws;                        // slot 0
  float* Y  = ws + (size_t)1 * 1048576;  // slot 1
  float* S  = ws + (size_t)2 * 1048576;  // slot 2
  float* F  = ws + (size_t)3 * 1048576;  // slot 3
  unsigned short* Pbf = (unsigned short*)(ws + (size_t)4 * 1048576);  // slots 4-7 [4096][2048]
  unsigned short* Cb  = Pbf;             // alias: attn block b reads P[b] fully before writing C[b]
  unsigned short* Sb  = (unsigned short*)(ws + (size_t)8 * 1048576);  // slot 8
  unsigned short* HHb = (unsigned short*)(ws + (size_t)9 * 1048576);  // slots 9-10
  unsigned short* Xb  = (unsigned short*)(ws + (size_t)11 * 1048576); // slot 11
  char* wb = (char*)(ws + (size_t)12 * 1048576);
  unsigned short* W1t = (unsigned short*)(wb);                        // 512 KiB
  unsigned short* W2t = (unsigned short*)(wb + (512u << 10));         // 512 KiB
  unsigned short* Mt  = (unsigned short*)(wb + (1024u << 10));        // 1 MiB
  unsigned short* Gt  = (unsigned short*)(wb + (2048u << 10));        // 1 MiB
  float* pbv  = (float*)(wb + (3072u << 10));                         // 8 KiB
  float* bo2  = (float*)(wb + (3072u << 10) + 8192);                  // 1 KiB
  int*   flagsArr = (int*)(wb + (3072u << 10) + 16384);               // 256 ints
  float* out = (float*)d_out;

  k_prep<<<1665, 256, 0, stream>>>(Wq, Wk, Wv, Wo, W1, W2, bq, bv, bo,
                                   batch, emb, (const unsigned int*)nei_mask,
                                   W1t, W2t, Mt, Gt, pbv, bo2, X, Xb, flagsArr);
  // P = Xb @ Mt^T + pb  [bf16 out], N=2048
  k_mgemm<128, 64, 2, true><<<dim3(2048 / 64, BQ / 128), 256, 0, stream>>>(Xb, Mt, pbv, Pbf, BQ, 2048, 256);
  k_attn<<<BQ, 256, 0, stream>>>(nei_idx, nei_mask, flagsArr, emb, Pbf, Cb);
  // Y = Cb @ Gt^T + bo2  [f32 out], K=2048
  k_mgemm<32, 64, 2, false><<<dim3(D / 64, BQ / 32), 256, 0, stream>>>(Cb, Gt, bo2, Y, BQ, D, 2048);
  k_ln<<<BQ, 256, 0, stream>>>(X, Y, ln1w, ln1b, S, Sb);
  // HH = relu(S@W1 + b1)  [bf16 out]
  k_mgemm<128, 64, 3, true><<<dim3(DFF / 64, BQ / 128), 256, 0, stream>>>(Sb, W1t, b1, HHb, BQ, DFF, 256);
  // F = relu(HH@W2 + b2)  [f32 out]
  k_mgemm<32, 64, 3, false><<<dim3(D / 64, BQ / 32), 256, 0, stream>>>(HHb, W2t, b2, F, BQ, D, DFF);
  k_ln<<<BQ, 256, 0, stream>>>(S, F, ln2w, ln2b, out, nullptr);
}